// Round 7
// baseline (296.201 us; speedup 1.0000x reference)
//
#include <hip/hip_runtime.h>
#include <math.h>

#define NV 8192
#define NE 4096
#define DIN 512
#define DH 256
#define CAP_E 96
#define CAP_V 64
#define NPROJ (NV / 32)      // 256 proj-GEMM blocks
#define NSCAN (NV / 2)       // 4096 scan blocks (4 waves/block, wave-per-half-row)

// ---------------- workspace layout (float offsets) ----------------
#define OFF_XH   0                       // V*DH fp32 (residual)
#define OFF_UB   (OFF_XH + NV*DH)        // V*DH bf16 (U = Xh@W^T)
#define OFF_YB   (OFF_UB + NV*DH/2)      // E*DH bf16
#define OFF_NCNT (OFF_YB + NE*DH/2)      // V ints
#define OFF_ECNT (OFF_NCNT + NV)         // E*16 ints (line-padded counters)
#define OFF_EL   (OFF_ECNT + NE*16)      // E*CAP_E ints
#define OFF_NL   (OFF_EL + NE*CAP_E)     // V*CAP_V ints
#define OFF_XHB  (OFF_NL + NV*CAP_V)     // V*DH bf16 (LN output bf16, feeds gemm_u / pool)

using bf16x8 = __attribute__((ext_vector_type(8))) short;
using f32x4  = __attribute__((ext_vector_type(4))) float;
using f32x4v = __attribute__((ext_vector_type(4))) float;

__device__ inline unsigned short f2bf(float f) {   // round-to-nearest-even
    union { float f; unsigned u; } v; v.f = f;
    unsigned r = v.u + 0x7FFF + ((v.u >> 16) & 1);
    return (unsigned short)(r >> 16);
}
__device__ inline float b2f(unsigned short s) {
    union { unsigned u; float f; } v; v.u = ((unsigned)s) << 16; return v.f;
}

// ---- U-GEMM from an LDS-stashed 32x256 bf16 A-tile (verified rounds 4-6) ----
__device__ inline void u_gemm_from_lds(const short* __restrict__ sm,
                                       const float* __restrict__ W,
                                       unsigned short* __restrict__ Ub,
                                       int bm, int tid) {
    const int w = tid >> 6, lane = tid & 63;
    const int r15 = lane & 15, k8 = (lane >> 4) << 3;
    const int swz = lane ^ ((lane >> 3) & 6);
    f32x4 acc[2][4];
#pragma unroll
    for (int mi = 0; mi < 2; ++mi)
#pragma unroll
        for (int ni = 0; ni < 4; ++ni) acc[mi][ni] = (f32x4){0.f, 0.f, 0.f, 0.f};
#pragma unroll
    for (int kc = 0; kc < 8; ++kc) {
        bf16x8 af[2], bfr[4];
        af[0] = *(const bf16x8*)&sm[(0 * 8 + kc) * 512 + swz * 8];
        af[1] = *(const bf16x8*)&sm[(1 * 8 + kc) * 512 + swz * 8];
#pragma unroll
        for (int ni = 0; ni < 4; ++ni) {
            const float* wr = W + (size_t)(w * 64 + ni * 16 + r15) * DH + kc * 32 + k8;
            float4 b0 = *(const float4*)wr;
            float4 b1 = *(const float4*)(wr + 4);
            bf16x8 bv;
            bv[0] = (short)f2bf(b0.x); bv[1] = (short)f2bf(b0.y);
            bv[2] = (short)f2bf(b0.z); bv[3] = (short)f2bf(b0.w);
            bv[4] = (short)f2bf(b1.x); bv[5] = (short)f2bf(b1.y);
            bv[6] = (short)f2bf(b1.z); bv[7] = (short)f2bf(b1.w);
            bfr[ni] = bv;
        }
#pragma unroll
        for (int mi = 0; mi < 2; ++mi)
#pragma unroll
            for (int ni = 0; ni < 4; ++ni)
                acc[mi][ni] = __builtin_amdgcn_mfma_f32_16x16x32_bf16(
                    af[mi], bfr[ni], acc[mi][ni], 0, 0, 0);
    }
    const int quad = lane >> 4, cl = lane & 15;
#pragma unroll
    for (int mi = 0; mi < 2; ++mi)
#pragma unroll
        for (int ni = 0; ni < 4; ++ni)
#pragma unroll
            for (int r = 0; r < 4; ++r)
                Ub[(size_t)(bm + mi * 16 + quad * 4 + r) * DH + w * 64 + ni * 16 + cl]
                    = f2bf(acc[mi][ni][r]);
}

// ---- fused: proj GEMM + U0 (blocks 0..NPROJ) | H scan (rest) — round-6 verbatim ----
__global__ __launch_bounds__(256) void scan_proj(const float* __restrict__ H,
                                                 const float* __restrict__ X,
                                                 const float* __restrict__ Wp,
                                                 const float* __restrict__ W0,
                                                 float* __restrict__ Xh,
                                                 unsigned short* __restrict__ Ub,
                                                 int* __restrict__ edge_cnt,
                                                 int* __restrict__ node_cnt,
                                                 int* __restrict__ edge_list,
                                                 int* __restrict__ node_list) {
    __shared__ short AsBs[1024 + 8192];
    const int tid = threadIdx.x;
    if (blockIdx.x >= NPROJ) {
        const int w = tid >> 6, lane = tid & 63;
        const int v    = (blockIdx.x - NPROJ) * 2 + (w >> 1);
        const int half = w & 1;
        const f32x4v* H4 = (const f32x4v*)(H + (size_t)v * NE) + half * 512;
        f32x4v h[8];
#pragma unroll
        for (int it = 0; it < 8; ++it)
            h[it] = __builtin_nontemporal_load(&H4[lane + 64 * it]);
        unsigned m = 0u;
#pragma unroll
        for (int it = 0; it < 8; ++it) {
#pragma unroll
            for (int c = 0; c < 4; ++c)
                m |= (h[it][c] != 0.0f ? 1u : 0u) << (it * 4 + c);
        }
        int n = __builtin_popcount(m);
        int pre = n;
#pragma unroll
        for (int o = 1; o < 64; o <<= 1) {
            int t = __shfl_up(pre, o, 64);
            if (lane >= o) pre += t;
        }
        int total = __shfl(pre, 63, 64);
        int local = pre - n;
        int base = 0;
        if (lane == 0 && total > 0) base = atomicAdd(&node_cnt[v], total);
        base = __shfl(base, 0, 64) + local;
        const int ebase = half * 2048 + 4 * lane;
        int e_arr[4] = {0, 0, 0, 0};
        {
            unsigned mm = m;
#pragma unroll
            for (int u = 0; u < 4; ++u) {
                if (mm) {
                    int j = __builtin_ctz(mm);
                    mm &= mm - 1;
                    e_arr[u] = ebase + 256 * (j >> 2) + (j & 3);
                }
            }
        }
        int s_arr[4];
#pragma unroll
        for (int u = 0; u < 4; ++u)
            s_arr[u] = (u < n) ? atomicAdd(&edge_cnt[e_arr[u] << 4], 1) : 0;
#pragma unroll
        for (int u = 0; u < 4; ++u) {
            if (u < n) {
                if (s_arr[u] < CAP_E) edge_list[e_arr[u] * CAP_E + s_arr[u]] = v;
                int idx = base + u;
                if (idx < CAP_V) node_list[v * CAP_V + idx] = e_arr[u];
            }
        }
        if (n > 4) {
            unsigned mm = m;
            mm &= mm - 1; mm &= mm - 1; mm &= mm - 1; mm &= mm - 1;
            int k = 4;
            while (mm) {
                int j = __builtin_ctz(mm); mm &= mm - 1;
                int ee = ebase + 256 * (j >> 2) + (j & 3);
                int gc = atomicAdd(&edge_cnt[ee << 4], 1);
                if (gc < CAP_E) edge_list[ee * CAP_E + gc] = v;
                int idx = base + k;
                if (idx < CAP_V) node_list[v * CAP_V + idx] = ee;
                ++k;
            }
        }
        return;
    }
    short* As = AsBs;
    short* Bs = AsBs + 1024;
    const int K = DIN;
    const int lane = tid & 63;
    const int w    = tid >> 6;
    const int bm   = blockIdx.x * 32;
    const int swz  = lane ^ ((lane >> 3) & 6);
    float4 ar, br[8];
    ar = *(const float4*)(X + (size_t)(bm + (tid >> 3)) * K + ((tid & 7) << 2));
#pragma unroll
    for (int it = 0; it < 8; ++it) {
        int i = tid + it * 256;
        br[it] = *(const float4*)(Wp + (size_t)(i >> 3) * K + ((i & 7) << 2));
    }
    f32x4 acc[2][4];
#pragma unroll
    for (int mi = 0; mi < 2; ++mi)
#pragma unroll
        for (int ni = 0; ni < 4; ++ni) acc[mi][ni] = (f32x4){0.f, 0.f, 0.f, 0.f};
    for (int k0 = 0; k0 < K; k0 += 32) {
        __syncthreads();
        {
            int row = tid >> 3, kk = (tid & 7) << 2;
            int quad = kk >> 3, j = kk & 7;
            int ln = (row & 15) + (quad << 4);
            int pp = ln ^ ((ln >> 3) & 6);
            ushort4 u = {f2bf(ar.x), f2bf(ar.y), f2bf(ar.z), f2bf(ar.w)};
            *(ushort4*)&As[(row >> 4) * 512 + pp * 8 + j] = u;
        }
#pragma unroll
        for (int it = 0; it < 8; ++it) {
            int i = tid + it * 256;
            int row = i >> 3, kk = (i & 7) << 2;
            int quad = kk >> 3, j = kk & 7;
            int ln = (row & 15) + (quad << 4);
            int pp = ln ^ ((ln >> 3) & 6);
            float4 v = br[it];
            ushort4 u = {f2bf(v.x), f2bf(v.y), f2bf(v.z), f2bf(v.w)};
            *(ushort4*)&Bs[(row >> 4) * 512 + pp * 8 + j] = u;
        }
        __syncthreads();
        if (k0 + 32 < K) {
            int kn = k0 + 32;
            ar = *(const float4*)(X + (size_t)(bm + (tid >> 3)) * K + kn + ((tid & 7) << 2));
#pragma unroll
            for (int it = 0; it < 8; ++it) {
                int i = tid + it * 256;
                br[it] = *(const float4*)(Wp + (size_t)(i >> 3) * K + kn + ((i & 7) << 2));
            }
        }
        bf16x8 af[2], bfr[4];
        af[0] = *(const bf16x8*)&As[0 * 512 + swz * 8];
        af[1] = *(const bf16x8*)&As[1 * 512 + swz * 8];
#pragma unroll
        for (int ni = 0; ni < 4; ++ni)
            bfr[ni] = *(const bf16x8*)&Bs[(w * 4 + ni) * 512 + swz * 8];
#pragma unroll
        for (int mi = 0; mi < 2; ++mi)
#pragma unroll
            for (int ni = 0; ni < 4; ++ni)
                acc[mi][ni] = __builtin_amdgcn_mfma_f32_16x16x32_bf16(
                    af[mi], bfr[ni], acc[mi][ni], 0, 0, 0);
    }
    const int quad = lane >> 4, cl = lane & 15;
    __syncthreads();
#pragma unroll
    for (int mi = 0; mi < 2; ++mi)
#pragma unroll
        for (int ni = 0; ni < 4; ++ni)
#pragma unroll
            for (int r = 0; r < 4; ++r) {
                float v = acc[mi][ni][r];
                int rl  = mi * 16 + quad * 4 + r;
                int col = w * 64 + ni * 16 + cl;
                Xh[(size_t)(bm + rl) * DH + col] = v;
                int kc = col >> 5, kk = col & 31;
                int q2 = kk >> 3, j = kk & 7;
                int ln = (rl & 15) + (q2 << 4);
                int pp = ln ^ ((ln >> 3) & 6);
                AsBs[(mi * 8 + kc) * 512 + pp * 8 + j] = (short)f2bf(v);
            }
    __syncthreads();
    u_gemm_from_lds(AsBs, W0, Ub, bm, tid);
}

// ------- gemm_u (round-0 verbatim) -------
__global__ __launch_bounds__(256) void gemm_u(const unsigned short* __restrict__ A,
                                              const float* __restrict__ W,
                                              unsigned short* __restrict__ U) {
    const int K = DH;
    __shared__ short As[2048];
    __shared__ short Bs[16384];
    const int tid  = threadIdx.x;
    const int lane = tid & 63;
    const int w    = tid >> 6;
    const int bm   = blockIdx.x * 32;
    const int swz  = lane ^ ((lane >> 3) & 6);

    uint4 ar; float4 br[16];
    ar = *(const uint4*)(A + (size_t)(bm + (tid >> 3)) * K + ((tid & 7) << 3));
#pragma unroll
    for (int it = 0; it < 16; ++it) {
        int i = tid + it * 256;
        br[it] = *(const float4*)(W + (size_t)(i >> 4) * K + ((i & 15) << 2));
    }
    f32x4 acc[2][4];
#pragma unroll
    for (int mi = 0; mi < 2; ++mi)
#pragma unroll
        for (int ni = 0; ni < 4; ++ni) acc[mi][ni] = (f32x4){0.f, 0.f, 0.f, 0.f};

    for (int k0 = 0; k0 < K; k0 += 64) {
        __syncthreads();
        {
            int row = tid >> 3, kq = tid & 7;
            int kc = kq >> 2, quad = kq & 3;
            int ln = (row & 15) + (quad << 4);
            int pp = ln ^ ((ln >> 3) & 6);
            *(uint4*)&As[((row >> 4) * 2 + kc) * 512 + pp * 8] = ar;
        }
#pragma unroll
        for (int it = 0; it < 16; ++it) {
            int i = tid + it * 256;
            int row = i >> 4, kk = (i & 15) << 2;
            int kc = kk >> 5, quad = (kk >> 3) & 3, j = kk & 7;
            int ln = (row & 15) + (quad << 4);
            int pp = ln ^ ((ln >> 3) & 6);
            float4 v = br[it];
            ushort4 u = {f2bf(v.x), f2bf(v.y), f2bf(v.z), f2bf(v.w)};
            *(ushort4*)&Bs[((row >> 4) * 2 + kc) * 512 + pp * 8 + j] = u;
        }
        __syncthreads();
        if (k0 + 64 < K) {
            int kn = k0 + 64;
            ar = *(const uint4*)(A + (size_t)(bm + (tid >> 3)) * K + kn + ((tid & 7) << 3));
#pragma unroll
            for (int it = 0; it < 16; ++it) {
                int i = tid + it * 256;
                br[it] = *(const float4*)(W + (size_t)(i >> 4) * K + kn + ((i & 15) << 2));
            }
        }
#pragma unroll
        for (int kc = 0; kc < 2; ++kc) {
            bf16x8 af[2], bfr[4];
            af[0] = *(const bf16x8*)&As[(0 * 2 + kc) * 512 + swz * 8];
            af[1] = *(const bf16x8*)&As[(1 * 2 + kc) * 512 + swz * 8];
#pragma unroll
            for (int ni = 0; ni < 4; ++ni)
                bfr[ni] = *(const bf16x8*)&Bs[((w * 4 + ni) * 2 + kc) * 512 + swz * 8];
#pragma unroll
            for (int mi = 0; mi < 2; ++mi)
#pragma unroll
                for (int ni = 0; ni < 4; ++ni)
                    acc[mi][ni] = __builtin_amdgcn_mfma_f32_16x16x32_bf16(
                        af[mi], bfr[ni], acc[mi][ni], 0, 0, 0);
        }
    }
    const int quad = lane >> 4, cl = lane & 15;
#pragma unroll
    for (int mi = 0; mi < 2; ++mi)
#pragma unroll
        for (int ni = 0; ni < 4; ++ni)
#pragma unroll
            for (int r = 0; r < 4; ++r)
                U[(size_t)(bm + mi * 16 + quad * 4 + r) * DH + w * 64 + ni * 16 + cl]
                    = f2bf(acc[mi][ni][r]);
}

// ---- edge gather, 2 waves per edge (even/odd rows), LDS combine.
//      Halves the dependent-load chain AND doubles waves/CU (grid 2048 -> 32 w/CU). ----
__global__ __launch_bounds__(256) void edge_gather2(const unsigned short* __restrict__ Ub,
                                                    const int* __restrict__ edge_cnt,
                                                    const int* __restrict__ edge_list,
                                                    const int* __restrict__ node_cnt,
                                                    unsigned short* __restrict__ Yb) {
    const int tid = threadIdx.x;
    const int w = tid >> 6, lane = tid & 63;
    const int es = w >> 1;           // edge slot in block (0/1)
    const int par = w & 1;           // wave parity: even/odd member rows
    const int e = blockIdx.x * 2 + es;
    __shared__ int    lv[2][CAP_E];
    __shared__ float  lc[2][CAP_E];
    __shared__ float4 part[2][64];
    int tc = edge_cnt[e << 4];
    int cnt = min(tc, CAP_E);
    for (int j = (par << 6) + lane; j < cnt; j += 128) {
        int v = edge_list[e * CAP_E + j];
        lv[es][j] = v * (DH / 4);
        lc[es][j] = rsqrtf((float)node_cnt[v]);
    }
    __syncthreads();
    const ushort4* X4 = (const ushort4*)Ub;
    float4 a[8];
#pragma unroll
    for (int u = 0; u < 8; ++u) a[u] = (float4){0.f, 0.f, 0.f, 0.f};
    const int nw = (cnt > par) ? ((cnt - par + 1) >> 1) : 0;  // rows par, par+2, ...
    int i = 0;
    for (; i + 8 <= nw; i += 8) {
#pragma unroll
        for (int u = 0; u < 8; ++u) {
            int r = par + ((i + u) << 1);
            ushort4 h = X4[lv[es][r] + lane]; float c = lc[es][r];
            a[u].x = fmaf(c, b2f(h.x), a[u].x); a[u].y = fmaf(c, b2f(h.y), a[u].y);
            a[u].z = fmaf(c, b2f(h.z), a[u].z); a[u].w = fmaf(c, b2f(h.w), a[u].w);
        }
    }
    for (; i < nw; ++i) {
        int r = par + (i << 1);
        ushort4 h = X4[lv[es][r] + lane]; float c = lc[es][r];
        a[0].x = fmaf(c, b2f(h.x), a[0].x); a[0].y = fmaf(c, b2f(h.y), a[0].y);
        a[0].z = fmaf(c, b2f(h.z), a[0].z); a[0].w = fmaf(c, b2f(h.w), a[0].w);
    }
#pragma unroll
    for (int u = 4; u > 0; u >>= 1)
#pragma unroll
        for (int q = 0; q < u; ++q) {
            a[q].x += a[q + u].x; a[q].y += a[q + u].y;
            a[q].z += a[q + u].z; a[q].w += a[q + u].w;
        }
    if (par) part[es][lane] = a[0];
    __syncthreads();
    if (!par) {
        float4 p = part[es][lane];
        a[0].x += p.x; a[0].y += p.y; a[0].z += p.z; a[0].w += p.w;
        float de = tc > 0 ? rsqrtf((float)tc) : 0.f;
        ushort4 o = {f2bf(de * a[0].x), f2bf(de * a[0].y),
                     f2bf(de * a[0].z), f2bf(de * a[0].w)};
        ((ushort4*)Yb)[e * (DH / 4) + lane] = o;
    }
}

// ---- node gather + relu + residual + LayerNorm: one node per wave (round-6 verbatim) ----
__global__ __launch_bounds__(256) void node_ln4(const unsigned short* __restrict__ Yb,
                                                const int* __restrict__ node_cnt,
                                                const int* __restrict__ node_list,
                                                const int* __restrict__ edge_cnt,
                                                float* __restrict__ Xh,
                                                unsigned short* __restrict__ Xhb,
                                                const float* __restrict__ g,
                                                const float* __restrict__ b) {
    const int tid = threadIdx.x;
    const int w = tid >> 6, lane = tid & 63;
    const int v = blockIdx.x * 4 + w;
    __shared__ int   le[4][CAP_V];
    __shared__ float lc[4][CAP_V];
    int tc = node_cnt[v];
    int cnt = min(tc, CAP_V);
    if (lane < cnt) {
        int e = node_list[v * CAP_V + lane];
        le[w][lane] = e * (DH / 4);
        lc[w][lane] = rsqrtf((float)edge_cnt[e << 4]);
    }
    __syncthreads();
    const ushort4* Y4 = (const ushort4*)Yb;
    float4 a[8];
#pragma unroll
    for (int u = 0; u < 8; ++u) a[u] = (float4){0.f, 0.f, 0.f, 0.f};
    int i = 0;
    for (; i + 8 <= cnt; i += 8) {
#pragma unroll
        for (int u = 0; u < 8; ++u) {
            ushort4 h = Y4[le[w][i + u] + lane]; float c = lc[w][i + u];
            a[u].x = fmaf(c, b2f(h.x), a[u].x); a[u].y = fmaf(c, b2f(h.y), a[u].y);
            a[u].z = fmaf(c, b2f(h.z), a[u].z); a[u].w = fmaf(c, b2f(h.w), a[u].w);
        }
    }
    for (; i < cnt; ++i) {
        ushort4 h = Y4[le[w][i] + lane]; float c = lc[w][i];
        a[0].x = fmaf(c, b2f(h.x), a[0].x); a[0].y = fmaf(c, b2f(h.y), a[0].y);
        a[0].z = fmaf(c, b2f(h.z), a[0].z); a[0].w = fmaf(c, b2f(h.w), a[0].w);
    }
#pragma unroll
    for (int u = 4; u > 0; u >>= 1)
#pragma unroll
        for (int q = 0; q < u; ++q) {
            a[q].x += a[q + u].x; a[q].y += a[q + u].y;
            a[q].z += a[q + u].z; a[q].w += a[q + u].w;
        }
    float dv = tc > 0 ? rsqrtf((float)tc) : 0.f;
    float4 xr = ((const float4*)Xh)[v * (DH / 4) + lane];
    float x0 = xr.x + fmaxf(dv * a[0].x, 0.f);
    float x1 = xr.y + fmaxf(dv * a[0].y, 0.f);
    float x2 = xr.z + fmaxf(dv * a[0].z, 0.f);
    float x3 = xr.w + fmaxf(dv * a[0].w, 0.f);
    float s = (x0 + x1) + (x2 + x3);
    float q = fmaf(x0, x0, fmaf(x1, x1, fmaf(x2, x2, x3 * x3)));
#pragma unroll
    for (int o = 1; o < 64; o <<= 1) {
        s += __shfl_xor(s, o, 64);
        q += __shfl_xor(q, o, 64);
    }
    float m = s * (1.0f / DH);
    float var = q * (1.0f / DH) - m * m;
    float rstd = rsqrtf(var + 1e-5f);
    float4 g4 = ((const float4*)g)[lane];
    float4 b4 = ((const float4*)b)[lane];
    float4 o;
    o.x = (x0 - m) * rstd * g4.x + b4.x;
    o.y = (x1 - m) * rstd * g4.y + b4.y;
    o.z = (x2 - m) * rstd * g4.z + b4.z;
    o.w = (x3 - m) * rstd * g4.w + b4.w;
    ((float4*)Xh)[v * (DH / 4) + lane] = o;
    ushort4 ob = {f2bf(o.x), f2bf(o.y), f2bf(o.z), f2bf(o.w)};
    ((ushort4*)Xhb)[v * (DH / 4) + lane] = ob;
}

// ------- mean-pool + classifier + softmax: 2 waves per edge, LDS combine -------
__global__ __launch_bounds__(256) void pool_classify2(const unsigned short* __restrict__ Xhb,
                                                      const int* __restrict__ edge_cnt,
                                                      const int* __restrict__ edge_list,
                                                      const float* __restrict__ Wc,
                                                      const float* __restrict__ bc,
                                                      float* __restrict__ out) {
    const int tid = threadIdx.x;
    const int w = tid >> 6, lane = tid & 63;
    const int es = w >> 1;
    const int par = w & 1;
    const int e = blockIdx.x * 2 + es;
    __shared__ int    lv[2][CAP_E];
    __shared__ float4 part[2][64];
    int tc = edge_cnt[e << 4];
    int cnt = min(tc, CAP_E);
    for (int j = (par << 6) + lane; j < cnt; j += 128)
        lv[es][j] = edge_list[e * CAP_E + j] * (DH / 4);
    __syncthreads();
    const ushort4* X4 = (const ushort4*)Xhb;
    float4 a[8];
#pragma unroll
    for (int u = 0; u < 8; ++u) a[u] = (float4){0, 0, 0, 0};
    const int nw = (cnt > par) ? ((cnt - par + 1) >> 1) : 0;
    int i = 0;
    for (; i + 8 <= nw; i += 8) {
#pragma unroll
        for (int u = 0; u < 8; ++u) {
            ushort4 h = X4[lv[es][par + ((i + u) << 1)] + lane];
            a[u].x += b2f(h.x); a[u].y += b2f(h.y);
            a[u].z += b2f(h.z); a[u].w += b2f(h.w);
        }
    }
    for (; i < nw; ++i) {
        ushort4 h = X4[lv[es][par + (i << 1)] + lane];
        a[0].x += b2f(h.x); a[0].y += b2f(h.y);
        a[0].z += b2f(h.z); a[0].w += b2f(h.w);
    }
#pragma unroll
    for (int u = 4; u > 0; u >>= 1)
#pragma unroll
        for (int q = 0; q < u; ++q) {
            a[q].x += a[q + u].x; a[q].y += a[q + u].y;
            a[q].z += a[q + u].z; a[q].w += a[q + u].w;
        }
    if (par) part[es][lane] = a[0];
    __syncthreads();
    if (!par) {
        float4 p = part[es][lane];
        a[0].x += p.x; a[0].y += p.y; a[0].z += p.z; a[0].w += p.w;
        float inv = tc > 0 ? 1.0f / (float)tc : 1.0f;
        float4 val = {a[0].x * inv, a[0].y * inv, a[0].z * inv, a[0].w * inv};
        const float4* W4 = (const float4*)Wc;
        float4 w0 = W4[lane], w1 = W4[64 + lane];
        float p0 = val.x * w0.x + val.y * w0.y + val.z * w0.z + val.w * w0.w;
        float p1 = val.x * w1.x + val.y * w1.y + val.z * w1.z + val.w * w1.w;
#pragma unroll
        for (int o = 32; o > 0; o >>= 1) {
            p0 += __shfl_down(p0, o, 64);
            p1 += __shfl_down(p1, o, 64);
        }
        if (lane == 0) {
            float l0 = p0 + bc[0], l1 = p1 + bc[1];
            float mx = fmaxf(l0, l1);
            float e0 = expf(l0 - mx), e1 = expf(l1 - mx);
            float s = 1.0f / (e0 + e1);
            out[e * 2 + 0] = e0 * s;
            out[e * 2 + 1] = e1 * s;
        }
    }
}

extern "C" void kernel_launch(void* const* d_in, const int* in_sizes, int n_in,
                              void* d_out, int out_size, void* d_ws, size_t ws_size,
                              hipStream_t stream) {
    const float* X  = (const float*)d_in[0];
    const float* H  = (const float*)d_in[1];
    const float* Wp = (const float*)d_in[2];
    const float* W0 = (const float*)d_in[3];
    const float* W1 = (const float*)d_in[4];
    const float* g0 = (const float*)d_in[5];
    const float* b0 = (const float*)d_in[6];
    const float* g1 = (const float*)d_in[7];
    const float* b1 = (const float*)d_in[8];
    const float* Wc = (const float*)d_in[9];
    const float* bc = (const float*)d_in[10];
    float* out = (float*)d_out;

    float* ws = (float*)d_ws;
    float* Xh  = ws + OFF_XH;
    unsigned short* Ub  = (unsigned short*)(ws + OFF_UB);
    unsigned short* Yb  = (unsigned short*)(ws + OFF_YB);
    int* node_cnt  = (int*)(ws + OFF_NCNT);
    int* edge_cnt  = (int*)(ws + OFF_ECNT);
    int* edge_list = (int*)(ws + OFF_EL);
    int* node_list = (int*)(ws + OFF_NL);
    unsigned short* Xhb = (unsigned short*)(ws + OFF_XHB);

    hipMemsetAsync(node_cnt, 0, (size_t)(NV + NE * 16) * sizeof(int), stream);

    // stage A: proj GEMM + fused U0 (hides under the 4096-block scan)
    scan_proj<<<NPROJ + NSCAN, 256, 0, stream>>>(H, X, Wp, W0, Xh, Ub,
                                                 edge_cnt, node_cnt, edge_list, node_list);

    // layer 0
    edge_gather2<<<NE / 2, 256, 0, stream>>>(Ub, edge_cnt, edge_list, node_cnt, Yb);
    node_ln4<<<NV / 4, 256, 0, stream>>>(Yb, node_cnt, node_list, edge_cnt,
                                         Xh, Xhb, g0, b0);
    // layer 1
    gemm_u<<<NV / 32, 256, 0, stream>>>(Xhb, W1, Ub);
    edge_gather2<<<NE / 2, 256, 0, stream>>>(Ub, edge_cnt, edge_list, node_cnt, Yb);
    node_ln4<<<NV / 4, 256, 0, stream>>>(Yb, node_cnt, node_list, edge_cnt,
                                         Xh, Xhb, g1, b1);

    pool_classify2<<<NE / 2, 256, 0, stream>>>(Xhb, edge_cnt, edge_list, Wc, bc, out);
}

// Round 8
// 287.202 us; speedup vs baseline: 1.0313x; 1.0313x over previous
//
#include <hip/hip_runtime.h>
#include <math.h>

#define NV 8192
#define NE 4096
#define DIN 512
#define DH 256
#define CAP_E 96
#define CAP_V 64
#define NPROJ (NV / 32)      // 256 proj-GEMM blocks
#define NSCAN (NV / 2)       // 4096 scan blocks (4 waves/block, wave-per-half-row)

// ---------------- workspace layout (float offsets) ----------------
#define OFF_XH   0                       // V*DH fp32 (residual)
#define OFF_UB   (OFF_XH + NV*DH)        // V*DH bf16 (U = Xh@W^T)
#define OFF_YB   (OFF_UB + NV*DH/2)      // E*DH bf16
#define OFF_NCNT (OFF_YB + NE*DH/2)      // V ints
#define OFF_ECNT (OFF_NCNT + NV)         // E*16 ints (line-padded counters)
#define OFF_EL   (OFF_ECNT + NE*16)      // E*CAP_E ints
#define OFF_NL   (OFF_EL + NE*CAP_E)     // V*CAP_V ints
#define OFF_XHB  (OFF_NL + NV*CAP_V)     // V*DH bf16 (LN output bf16, feeds gemm_u / pool)

using bf16x8 = __attribute__((ext_vector_type(8))) short;
using f32x4  = __attribute__((ext_vector_type(4))) float;
using f32x4v = __attribute__((ext_vector_type(4))) float;

__device__ inline unsigned short f2bf(float f) {   // round-to-nearest-even
    union { float f; unsigned u; } v; v.f = f;
    unsigned r = v.u + 0x7FFF + ((v.u >> 16) & 1);
    return (unsigned short)(r >> 16);
}
__device__ inline float b2f(unsigned short s) {
    union { unsigned u; float f; } v; v.u = ((unsigned)s) << 16; return v.f;
}

// ---- U-GEMM from an LDS-stashed 32x256 bf16 A-tile (verified rounds 4-7) ----
__device__ inline void u_gemm_from_lds(const short* __restrict__ sm,
                                       const float* __restrict__ W,
                                       unsigned short* __restrict__ Ub,
                                       int bm, int tid) {
    const int w = tid >> 6, lane = tid & 63;
    const int r15 = lane & 15, k8 = (lane >> 4) << 3;
    const int swz = lane ^ ((lane >> 3) & 6);
    f32x4 acc[2][4];
#pragma unroll
    for (int mi = 0; mi < 2; ++mi)
#pragma unroll
        for (int ni = 0; ni < 4; ++ni) acc[mi][ni] = (f32x4){0.f, 0.f, 0.f, 0.f};
#pragma unroll
    for (int kc = 0; kc < 8; ++kc) {
        bf16x8 af[2], bfr[4];
        af[0] = *(const bf16x8*)&sm[(0 * 8 + kc) * 512 + swz * 8];
        af[1] = *(const bf16x8*)&sm[(1 * 8 + kc) * 512 + swz * 8];
#pragma unroll
        for (int ni = 0; ni < 4; ++ni) {
            const float* wr = W + (size_t)(w * 64 + ni * 16 + r15) * DH + kc * 32 + k8;
            float4 b0 = *(const float4*)wr;
            float4 b1 = *(const float4*)(wr + 4);
            bf16x8 bv;
            bv[0] = (short)f2bf(b0.x); bv[1] = (short)f2bf(b0.y);
            bv[2] = (short)f2bf(b0.z); bv[3] = (short)f2bf(b0.w);
            bv[4] = (short)f2bf(b1.x); bv[5] = (short)f2bf(b1.y);
            bv[6] = (short)f2bf(b1.z); bv[7] = (short)f2bf(b1.w);
            bfr[ni] = bv;
        }
#pragma unroll
        for (int mi = 0; mi < 2; ++mi)
#pragma unroll
            for (int ni = 0; ni < 4; ++ni)
                acc[mi][ni] = __builtin_amdgcn_mfma_f32_16x16x32_bf16(
                    af[mi], bfr[ni], acc[mi][ni], 0, 0, 0);
    }
    const int quad = lane >> 4, cl = lane & 15;
#pragma unroll
    for (int mi = 0; mi < 2; ++mi)
#pragma unroll
        for (int ni = 0; ni < 4; ++ni)
#pragma unroll
            for (int r = 0; r < 4; ++r)
                Ub[(size_t)(bm + mi * 16 + quad * 4 + r) * DH + w * 64 + ni * 16 + cl]
                    = f2bf(acc[mi][ni][r]);
}

// ---- fused: blocks [0,NPROJ) proj GEMM Xh = X @ Wp^T (BK=32) + U0 = tile @ W0^T;
//      blocks [NPROJ, NPROJ+NSCAN): scan H, wave-per-half-row, batched atomics.
//      ROUND-8 CHANGE: H loads are CACHED (was nontemporal). H is read once;
//      LLC(256MB) pollution is harmless vs ~25MB of live intermediates, and the
//      NT path may throttle per-request read throughput. ----
__global__ __launch_bounds__(256) void scan_proj(const float* __restrict__ H,
                                                 const float* __restrict__ X,
                                                 const float* __restrict__ Wp,
                                                 const float* __restrict__ W0,
                                                 float* __restrict__ Xh,
                                                 unsigned short* __restrict__ Ub,
                                                 int* __restrict__ edge_cnt,
                                                 int* __restrict__ node_cnt,
                                                 int* __restrict__ edge_list,
                                                 int* __restrict__ node_list) {
    __shared__ short AsBs[1024 + 8192];
    const int tid = threadIdx.x;
    if (blockIdx.x >= NPROJ) {
        const int w = tid >> 6, lane = tid & 63;
        const int v    = (blockIdx.x - NPROJ) * 2 + (w >> 1);
        const int half = w & 1;
        const f32x4v* H4 = (const f32x4v*)(H + (size_t)v * NE) + half * 512;
        f32x4v h[8];
#pragma unroll
        for (int it = 0; it < 8; ++it)
            h[it] = H4[lane + 64 * it];   // cached loads (round-8 single change)
        unsigned m = 0u;
#pragma unroll
        for (int it = 0; it < 8; ++it) {
#pragma unroll
            for (int c = 0; c < 4; ++c)
                m |= (h[it][c] != 0.0f ? 1u : 0u) << (it * 4 + c);
        }
        int n = __builtin_popcount(m);
        int pre = n;
#pragma unroll
        for (int o = 1; o < 64; o <<= 1) {
            int t = __shfl_up(pre, o, 64);
            if (lane >= o) pre += t;
        }
        int total = __shfl(pre, 63, 64);
        int local = pre - n;
        int base = 0;
        if (lane == 0 && total > 0) base = atomicAdd(&node_cnt[v], total);
        base = __shfl(base, 0, 64) + local;
        const int ebase = half * 2048 + 4 * lane;
        int e_arr[4] = {0, 0, 0, 0};
        {
            unsigned mm = m;
#pragma unroll
            for (int u = 0; u < 4; ++u) {
                if (mm) {
                    int j = __builtin_ctz(mm);
                    mm &= mm - 1;
                    e_arr[u] = ebase + 256 * (j >> 2) + (j & 3);
                }
            }
        }
        int s_arr[4];
#pragma unroll
        for (int u = 0; u < 4; ++u)
            s_arr[u] = (u < n) ? atomicAdd(&edge_cnt[e_arr[u] << 4], 1) : 0;
#pragma unroll
        for (int u = 0; u < 4; ++u) {
            if (u < n) {
                if (s_arr[u] < CAP_E) edge_list[e_arr[u] * CAP_E + s_arr[u]] = v;
                int idx = base + u;
                if (idx < CAP_V) node_list[v * CAP_V + idx] = e_arr[u];
            }
        }
        if (n > 4) {
            unsigned mm = m;
            mm &= mm - 1; mm &= mm - 1; mm &= mm - 1; mm &= mm - 1;
            int k = 4;
            while (mm) {
                int j = __builtin_ctz(mm); mm &= mm - 1;
                int ee = ebase + 256 * (j >> 2) + (j & 3);
                int gc = atomicAdd(&edge_cnt[ee << 4], 1);
                if (gc < CAP_E) edge_list[ee * CAP_E + gc] = v;
                int idx = base + k;
                if (idx < CAP_V) node_list[v * CAP_V + idx] = ee;
                ++k;
            }
        }
        return;
    }
    // ---------------- proj GEMM path: BM=32, BN=256, BK=32, K=DIN ----------------
    short* As = AsBs;
    short* Bs = AsBs + 1024;
    const int K = DIN;
    const int lane = tid & 63;
    const int w    = tid >> 6;
    const int bm   = blockIdx.x * 32;
    const int swz  = lane ^ ((lane >> 3) & 6);
    float4 ar, br[8];
    ar = *(const float4*)(X + (size_t)(bm + (tid >> 3)) * K + ((tid & 7) << 2));
#pragma unroll
    for (int it = 0; it < 8; ++it) {
        int i = tid + it * 256;
        br[it] = *(const float4*)(Wp + (size_t)(i >> 3) * K + ((i & 7) << 2));
    }
    f32x4 acc[2][4];
#pragma unroll
    for (int mi = 0; mi < 2; ++mi)
#pragma unroll
        for (int ni = 0; ni < 4; ++ni) acc[mi][ni] = (f32x4){0.f, 0.f, 0.f, 0.f};
    for (int k0 = 0; k0 < K; k0 += 32) {
        __syncthreads();
        {
            int row = tid >> 3, kk = (tid & 7) << 2;
            int quad = kk >> 3, j = kk & 7;
            int ln = (row & 15) + (quad << 4);
            int pp = ln ^ ((ln >> 3) & 6);
            ushort4 u = {f2bf(ar.x), f2bf(ar.y), f2bf(ar.z), f2bf(ar.w)};
            *(ushort4*)&As[(row >> 4) * 512 + pp * 8 + j] = u;
        }
#pragma unroll
        for (int it = 0; it < 8; ++it) {
            int i = tid + it * 256;
            int row = i >> 3, kk = (i & 7) << 2;
            int quad = kk >> 3, j = kk & 7;
            int ln = (row & 15) + (quad << 4);
            int pp = ln ^ ((ln >> 3) & 6);
            float4 v = br[it];
            ushort4 u = {f2bf(v.x), f2bf(v.y), f2bf(v.z), f2bf(v.w)};
            *(ushort4*)&Bs[(row >> 4) * 512 + pp * 8 + j] = u;
        }
        __syncthreads();
        if (k0 + 32 < K) {
            int kn = k0 + 32;
            ar = *(const float4*)(X + (size_t)(bm + (tid >> 3)) * K + kn + ((tid & 7) << 2));
#pragma unroll
            for (int it = 0; it < 8; ++it) {
                int i = tid + it * 256;
                br[it] = *(const float4*)(Wp + (size_t)(i >> 3) * K + kn + ((i & 7) << 2));
            }
        }
        bf16x8 af[2], bfr[4];
        af[0] = *(const bf16x8*)&As[0 * 512 + swz * 8];
        af[1] = *(const bf16x8*)&As[1 * 512 + swz * 8];
#pragma unroll
        for (int ni = 0; ni < 4; ++ni)
            bfr[ni] = *(const bf16x8*)&Bs[(w * 4 + ni) * 512 + swz * 8];
#pragma unroll
        for (int mi = 0; mi < 2; ++mi)
#pragma unroll
            for (int ni = 0; ni < 4; ++ni)
                acc[mi][ni] = __builtin_amdgcn_mfma_f32_16x16x32_bf16(
                    af[mi], bfr[ni], acc[mi][ni], 0, 0, 0);
    }
    const int quad = lane >> 4, cl = lane & 15;
    __syncthreads();   // all waves done reading As/Bs before the U-stash reuses LDS
#pragma unroll
    for (int mi = 0; mi < 2; ++mi)
#pragma unroll
        for (int ni = 0; ni < 4; ++ni)
#pragma unroll
            for (int r = 0; r < 4; ++r) {
                float v = acc[mi][ni][r];
                int rl  = mi * 16 + quad * 4 + r;
                int col = w * 64 + ni * 16 + cl;
                Xh[(size_t)(bm + rl) * DH + col] = v;
                int kc = col >> 5, kk = col & 31;
                int q2 = kk >> 3, j = kk & 7;
                int ln = (rl & 15) + (q2 << 4);
                int pp = ln ^ ((ln >> 3) & 6);
                AsBs[(mi * 8 + kc) * 512 + pp * 8 + j] = (short)f2bf(v);
            }
    __syncthreads();
    u_gemm_from_lds(AsBs, W0, Ub, bm, tid);
}

// ------- U = bf16(Xhb @ W^T): bf16 A (no conversion), K=256, BM=32 (round-0 verbatim) ----
__global__ __launch_bounds__(256) void gemm_u(const unsigned short* __restrict__ A,
                                              const float* __restrict__ W,
                                              unsigned short* __restrict__ U) {
    const int K = DH;
    __shared__ short As[2048];
    __shared__ short Bs[16384];
    const int tid  = threadIdx.x;
    const int lane = tid & 63;
    const int w    = tid >> 6;
    const int bm   = blockIdx.x * 32;
    const int swz  = lane ^ ((lane >> 3) & 6);

    uint4 ar; float4 br[16];
    ar = *(const uint4*)(A + (size_t)(bm + (tid >> 3)) * K + ((tid & 7) << 3));
#pragma unroll
    for (int it = 0; it < 16; ++it) {
        int i = tid + it * 256;
        br[it] = *(const float4*)(W + (size_t)(i >> 4) * K + ((i & 15) << 2));
    }
    f32x4 acc[2][4];
#pragma unroll
    for (int mi = 0; mi < 2; ++mi)
#pragma unroll
        for (int ni = 0; ni < 4; ++ni) acc[mi][ni] = (f32x4){0.f, 0.f, 0.f, 0.f};

    for (int k0 = 0; k0 < K; k0 += 64) {
        __syncthreads();
        {
            int row = tid >> 3, kq = tid & 7;
            int kc = kq >> 2, quad = kq & 3;
            int ln = (row & 15) + (quad << 4);
            int pp = ln ^ ((ln >> 3) & 6);
            *(uint4*)&As[((row >> 4) * 2 + kc) * 512 + pp * 8] = ar;
        }
#pragma unroll
        for (int it = 0; it < 16; ++it) {
            int i = tid + it * 256;
            int row = i >> 4, kk = (i & 15) << 2;
            int kc = kk >> 5, quad = (kk >> 3) & 3, j = kk & 7;
            int ln = (row & 15) + (quad << 4);
            int pp = ln ^ ((ln >> 3) & 6);
            float4 v = br[it];
            ushort4 u = {f2bf(v.x), f2bf(v.y), f2bf(v.z), f2bf(v.w)};
            *(ushort4*)&Bs[((row >> 4) * 2 + kc) * 512 + pp * 8 + j] = u;
        }
        __syncthreads();
        if (k0 + 64 < K) {
            int kn = k0 + 64;
            ar = *(const uint4*)(A + (size_t)(bm + (tid >> 3)) * K + kn + ((tid & 7) << 3));
#pragma unroll
            for (int it = 0; it < 16; ++it) {
                int i = tid + it * 256;
                br[it] = *(const float4*)(W + (size_t)(i >> 4) * K + kn + ((i & 15) << 2));
            }
        }
#pragma unroll
        for (int kc = 0; kc < 2; ++kc) {
            bf16x8 af[2], bfr[4];
            af[0] = *(const bf16x8*)&As[(0 * 2 + kc) * 512 + swz * 8];
            af[1] = *(const bf16x8*)&As[(1 * 2 + kc) * 512 + swz * 8];
#pragma unroll
            for (int ni = 0; ni < 4; ++ni)
                bfr[ni] = *(const bf16x8*)&Bs[((w * 4 + ni) * 2 + kc) * 512 + swz * 8];
#pragma unroll
            for (int mi = 0; mi < 2; ++mi)
#pragma unroll
                for (int ni = 0; ni < 4; ++ni)
                    acc[mi][ni] = __builtin_amdgcn_mfma_f32_16x16x32_bf16(
                        af[mi], bfr[ni], acc[mi][ni], 0, 0, 0);
        }
    }
    const int quad = lane >> 4, cl = lane & 15;
#pragma unroll
    for (int mi = 0; mi < 2; ++mi)
#pragma unroll
        for (int ni = 0; ni < 4; ++ni)
#pragma unroll
            for (int r = 0; r < 4; ++r)
                U[(size_t)(bm + mi * 16 + quad * 4 + r) * DH + w * 64 + ni * 16 + cl]
                    = f2bf(acc[mi][ni][r]);
}

// ---- Yb[e,:] = bf16( rsqrt(de) * sum_{v in e} rsqrt(dv) * Ub[v,:] ) (round-0 verbatim) ----
__global__ __launch_bounds__(64) void edge_gather(const unsigned short* __restrict__ Ub,
                                                  const int* __restrict__ edge_cnt,
                                                  const int* __restrict__ edge_list,
                                                  const int* __restrict__ node_cnt,
                                                  unsigned short* __restrict__ Yb) {
    int e = blockIdx.x;
    int tid = threadIdx.x;
    __shared__ int   lv[CAP_E];
    __shared__ float lc[CAP_E];
    int tc = edge_cnt[e << 4];
    int cnt = min(tc, CAP_E);
    for (int j = tid; j < cnt; j += 64) {
        int v = edge_list[e * CAP_E + j];
        lv[j] = v * (DH / 4);
        lc[j] = rsqrtf((float)node_cnt[v]);
    }
    __syncthreads();
    const ushort4* X4 = (const ushort4*)Ub;
    float4 a[8];
#pragma unroll
    for (int u = 0; u < 8; ++u) a[u] = (float4){0.f, 0.f, 0.f, 0.f};
    int i = 0;
    for (; i + 8 <= cnt; i += 8) {
#pragma unroll
        for (int u = 0; u < 8; ++u) {
            ushort4 h = X4[lv[i + u] + tid]; float c = lc[i + u];
            a[u].x = fmaf(c, b2f(h.x), a[u].x); a[u].y = fmaf(c, b2f(h.y), a[u].y);
            a[u].z = fmaf(c, b2f(h.z), a[u].z); a[u].w = fmaf(c, b2f(h.w), a[u].w);
        }
    }
    for (; i < cnt; ++i) {
        ushort4 h = X4[lv[i] + tid]; float c = lc[i];
        a[0].x = fmaf(c, b2f(h.x), a[0].x); a[0].y = fmaf(c, b2f(h.y), a[0].y);
        a[0].z = fmaf(c, b2f(h.z), a[0].z); a[0].w = fmaf(c, b2f(h.w), a[0].w);
    }
#pragma unroll
    for (int u = 4; u > 0; u >>= 1)
#pragma unroll
        for (int q = 0; q < u; ++q) {
            a[q].x += a[q + u].x; a[q].y += a[q + u].y;
            a[q].z += a[q + u].z; a[q].w += a[q + u].w;
        }
    float de = tc > 0 ? rsqrtf((float)tc) : 0.f;
    ushort4 o = {f2bf(de * a[0].x), f2bf(de * a[0].y),
                 f2bf(de * a[0].z), f2bf(de * a[0].w)};
    ((ushort4*)Yb)[e * (DH / 4) + tid] = o;
}

// ---- node gather + relu + residual + LayerNorm, one wave per row (round-0 verbatim) ----
__global__ __launch_bounds__(64) void node_ln(const unsigned short* __restrict__ Yb,
                                              const int* __restrict__ node_cnt,
                                              const int* __restrict__ node_list,
                                              const int* __restrict__ edge_cnt,
                                              float* __restrict__ Xh,
                                              unsigned short* __restrict__ Xhb,
                                              const float* __restrict__ g,
                                              const float* __restrict__ b) {
    int v = blockIdx.x;
    int tid = threadIdx.x;
    __shared__ int   le[CAP_V];
    __shared__ float lc[CAP_V];
    int tc = node_cnt[v];
    int cnt = min(tc, CAP_V);
    if (tid < cnt) {
        int e = node_list[v * CAP_V + tid];
        le[tid] = e * (DH / 4);
        lc[tid] = rsqrtf((float)edge_cnt[e << 4]);
    }
    __syncthreads();
    const ushort4* Y4 = (const ushort4*)Yb;
    float4 a[8];
#pragma unroll
    for (int u = 0; u < 8; ++u) a[u] = (float4){0.f, 0.f, 0.f, 0.f};
    int i = 0;
    for (; i + 8 <= cnt; i += 8) {
#pragma unroll
        for (int u = 0; u < 8; ++u) {
            ushort4 h = Y4[le[i + u] + tid]; float c = lc[i + u];
            a[u].x = fmaf(c, b2f(h.x), a[u].x); a[u].y = fmaf(c, b2f(h.y), a[u].y);
            a[u].z = fmaf(c, b2f(h.z), a[u].z); a[u].w = fmaf(c, b2f(h.w), a[u].w);
        }
    }
    for (; i < cnt; ++i) {
        ushort4 h = Y4[le[i] + tid]; float c = lc[i];
        a[0].x = fmaf(c, b2f(h.x), a[0].x); a[0].y = fmaf(c, b2f(h.y), a[0].y);
        a[0].z = fmaf(c, b2f(h.z), a[0].z); a[0].w = fmaf(c, b2f(h.w), a[0].w);
    }
#pragma unroll
    for (int u = 4; u > 0; u >>= 1)
#pragma unroll
        for (int q = 0; q < u; ++q) {
            a[q].x += a[q + u].x; a[q].y += a[q + u].y;
            a[q].z += a[q + u].z; a[q].w += a[q + u].w;
        }
    float dv = tc > 0 ? rsqrtf((float)tc) : 0.f;
    float4 xr = ((const float4*)Xh)[v * (DH / 4) + tid];
    float x0 = xr.x + fmaxf(dv * a[0].x, 0.f);
    float x1 = xr.y + fmaxf(dv * a[0].y, 0.f);
    float x2 = xr.z + fmaxf(dv * a[0].z, 0.f);
    float x3 = xr.w + fmaxf(dv * a[0].w, 0.f);
    float s = (x0 + x1) + (x2 + x3);
    float q = fmaf(x0, x0, fmaf(x1, x1, fmaf(x2, x2, x3 * x3)));
#pragma unroll
    for (int o = 1; o < 64; o <<= 1) {
        s += __shfl_xor(s, o, 64);
        q += __shfl_xor(q, o, 64);
    }
    float m = s * (1.0f / DH);
    float var = q * (1.0f / DH) - m * m;
    float rstd = rsqrtf(var + 1e-5f);
    float4 g4 = ((const float4*)g)[tid];
    float4 b4 = ((const float4*)b)[tid];
    float4 o;
    o.x = (x0 - m) * rstd * g4.x + b4.x;
    o.y = (x1 - m) * rstd * g4.y + b4.y;
    o.z = (x2 - m) * rstd * g4.z + b4.z;
    o.w = (x3 - m) * rstd * g4.w + b4.w;
    ((float4*)Xh)[v * (DH / 4) + tid] = o;
    ushort4 ob = {f2bf(o.x), f2bf(o.y), f2bf(o.z), f2bf(o.w)};
    ((ushort4*)Xhb)[v * (DH / 4) + tid] = ob;
}

// ------- fused mean-pool + classifier + softmax (64 thr, bf16 src) (round-0 verbatim) -------
__global__ __launch_bounds__(64) void pool_classify(const unsigned short* __restrict__ Xhb,
                                                    const int* __restrict__ edge_cnt,
                                                    const int* __restrict__ edge_list,
                                                    const float* __restrict__ Wc,
                                                    const float* __restrict__ bc,
                                                    float* __restrict__ out) {
    int e = blockIdx.x;
    int tid = threadIdx.x;
    __shared__ int lv[CAP_E];
    int tc = edge_cnt[e << 4];
    int cnt = min(tc, CAP_E);
    for (int j = tid; j < cnt; j += 64) lv[j] = edge_list[e * CAP_E + j] * (DH / 4);
    __syncthreads();
    const ushort4* X4 = (const ushort4*)Xhb;
    float4 a[8];
#pragma unroll
    for (int u = 0; u < 8; ++u) a[u] = (float4){0, 0, 0, 0};
    int i = 0;
    for (; i + 8 <= cnt; i += 8) {
#pragma unroll
        for (int u = 0; u < 8; ++u) {
            ushort4 h = X4[lv[i + u] + tid];
            a[u].x += b2f(h.x); a[u].y += b2f(h.y);
            a[u].z += b2f(h.z); a[u].w += b2f(h.w);
        }
    }
    for (; i < cnt; ++i) {
        ushort4 h = X4[lv[i] + tid];
        a[0].x += b2f(h.x); a[0].y += b2f(h.y);
        a[0].z += b2f(h.z); a[0].w += b2f(h.w);
    }
#pragma unroll
    for (int u = 4; u > 0; u >>= 1)
#pragma unroll
        for (int q = 0; q < u; ++q) {
            a[q].x += a[q + u].x; a[q].y += a[q + u].y;
            a[q].z += a[q + u].z; a[q].w += a[q + u].w;
        }
    float inv = tc > 0 ? 1.0f / (float)tc : 1.0f;
    float4 val = {a[0].x * inv, a[0].y * inv, a[0].z * inv, a[0].w * inv};
    const float4* W4 = (const float4*)Wc;
    float4 w0 = W4[tid], w1 = W4[64 + tid];
    float p0 = val.x * w0.x + val.y * w0.y + val.z * w0.z + val.w * w0.w;
    float p1 = val.x * w1.x + val.y * w1.y + val.z * w1.z + val.w * w1.w;
#pragma unroll
    for (int o = 32; o > 0; o >>= 1) {
        p0 += __shfl_down(p0, o, 64);
        p1 += __shfl_down(p1, o, 64);
    }
    if (tid == 0) {
        float l0 = p0 + bc[0], l1 = p1 + bc[1];
        float mx = fmaxf(l0, l1);
        float e0 = expf(l0 - mx), e1 = expf(l1 - mx);
        float s = 1.0f / (e0 + e1);
        out[e * 2 + 0] = e0 * s;
        out[e * 2 + 1] = e1 * s;
    }
}

extern "C" void kernel_launch(void* const* d_in, const int* in_sizes, int n_in,
                              void* d_out, int out_size, void* d_ws, size_t ws_size,
                              hipStream_t stream) {
    const float* X  = (const float*)d_in[0];
    const float* H  = (const float*)d_in[1];
    const float* Wp = (const float*)d_in[2];
    const float* W0 = (const float*)d_in[3];
    const float* W1 = (const float*)d_in[4];
    const float* g0 = (const float*)d_in[5];
    const float* b0 = (const float*)d_in[6];
    const float* g1 = (const float*)d_in[7];
    const float* b1 = (const float*)d_in[8];
    const float* Wc = (const float*)d_in[9];
    const float* bc = (const float*)d_in[10];
    float* out = (float*)d_out;

    float* ws = (float*)d_ws;
    float* Xh  = ws + OFF_XH;
    unsigned short* Ub  = (unsigned short*)(ws + OFF_UB);
    unsigned short* Yb  = (unsigned short*)(ws + OFF_YB);
    int* node_cnt  = (int*)(ws + OFF_NCNT);
    int* edge_cnt  = (int*)(ws + OFF_ECNT);
    int* edge_list = (int*)(ws + OFF_EL);
    int* node_list = (int*)(ws + OFF_NL);
    unsigned short* Xhb = (unsigned short*)(ws + OFF_XHB);

    // node_cnt and edge_cnt are contiguous: one memset for both
    hipMemsetAsync(node_cnt, 0, (size_t)(NV + NE * 16) * sizeof(int), stream);

    // stage A: proj GEMM + fused U0 (blocks 0..255, hides under the 4096-block scan)
    scan_proj<<<NPROJ + NSCAN, 256, 0, stream>>>(H, X, Wp, W0, Xh, Ub,
                                                 edge_cnt, node_cnt, edge_list, node_list);

    // layer 0 (U0 already in Ub)
    edge_gather<<<NE, 64, 0, stream>>>(Ub, edge_cnt, edge_list, node_cnt, Yb);
    node_ln<<<NV, 64, 0, stream>>>(Yb, node_cnt, node_list, edge_cnt,
                                   Xh, Xhb, g0, b0);
    // layer 1 (U1 from standalone high-occupancy gemm_u)
    gemm_u<<<NV / 32, 256, 0, stream>>>(Xhb, W1, Ub);
    edge_gather<<<NE, 64, 0, stream>>>(Ub, edge_cnt, edge_list, node_cnt, Yb);
    node_ln<<<NV, 64, 0, stream>>>(Yb, node_cnt, node_list, edge_cnt,
                                   Xh, Xhb, g1, b1);

    pool_classify<<<NE, 64, 0, stream>>>(Xhb, edge_cnt, edge_list, Wc, bc, out);
}

// Round 9
// 281.211 us; speedup vs baseline: 1.0533x; 1.0213x over previous
//
#include <hip/hip_runtime.h>
#include <math.h>

#define NV 8192
#define NE 4096
#define DIN 512
#define DH 256
#define CAP_E 96
#define CAP_V 64
#define NPROJ (NV / 32)      // 256 proj-GEMM blocks
#define NSCAN (NV / 2)       // 4096 scan blocks (4 waves/block, wave-per-half-row)

// ---------------- workspace layout (float offsets) ----------------
#define OFF_XH   0                       // V*DH fp32 (residual)
#define OFF_UB   (OFF_XH + NV*DH)        // V*DH bf16 (U = Xh@W^T)
#define OFF_YB   (OFF_UB + NV*DH/2)      // E*DH bf16
#define OFF_NCNT (OFF_YB + NE*DH/2)      // V ints
#define OFF_ECNT (OFF_NCNT + NV)         // E*16 ints (line-padded counters)
#define OFF_EL   (OFF_ECNT + NE*16)      // E*CAP_E ints
#define OFF_NL   (OFF_EL + NE*CAP_E)     // V*CAP_V ints
#define OFF_XHB  (OFF_NL + NV*CAP_V)     // V*DH bf16 (layer-0 LN out, feeds gemm_u)
#define OFF_Q    (OFF_XHB + NV*DH/2)     // V float2: per-node classifier dots

using bf16x8 = __attribute__((ext_vector_type(8))) short;
using f32x4  = __attribute__((ext_vector_type(4))) float;
using f32x4v = __attribute__((ext_vector_type(4))) float;

__device__ inline unsigned short f2bf(float f) {   // round-to-nearest-even
    union { float f; unsigned u; } v; v.f = f;
    unsigned r = v.u + 0x7FFF + ((v.u >> 16) & 1);
    return (unsigned short)(r >> 16);
}
__device__ inline float b2f(unsigned short s) {
    union { unsigned u; float f; } v; v.u = ((unsigned)s) << 16; return v.f;
}

// ---- U-GEMM from an LDS-stashed 32x256 bf16 A-tile (verified rounds 4-8) ----
__device__ inline void u_gemm_from_lds(const short* __restrict__ sm,
                                       const float* __restrict__ W,
                                       unsigned short* __restrict__ Ub,
                                       int bm, int tid) {
    const int w = tid >> 6, lane = tid & 63;
    const int r15 = lane & 15, k8 = (lane >> 4) << 3;
    const int swz = lane ^ ((lane >> 3) & 6);
    f32x4 acc[2][4];
#pragma unroll
    for (int mi = 0; mi < 2; ++mi)
#pragma unroll
        for (int ni = 0; ni < 4; ++ni) acc[mi][ni] = (f32x4){0.f, 0.f, 0.f, 0.f};
#pragma unroll
    for (int kc = 0; kc < 8; ++kc) {
        bf16x8 af[2], bfr[4];
        af[0] = *(const bf16x8*)&sm[(0 * 8 + kc) * 512 + swz * 8];
        af[1] = *(const bf16x8*)&sm[(1 * 8 + kc) * 512 + swz * 8];
#pragma unroll
        for (int ni = 0; ni < 4; ++ni) {
            const float* wr = W + (size_t)(w * 64 + ni * 16 + r15) * DH + kc * 32 + k8;
            float4 b0 = *(const float4*)wr;
            float4 b1 = *(const float4*)(wr + 4);
            bf16x8 bv;
            bv[0] = (short)f2bf(b0.x); bv[1] = (short)f2bf(b0.y);
            bv[2] = (short)f2bf(b0.z); bv[3] = (short)f2bf(b0.w);
            bv[4] = (short)f2bf(b1.x); bv[5] = (short)f2bf(b1.y);
            bv[6] = (short)f2bf(b1.z); bv[7] = (short)f2bf(b1.w);
            bfr[ni] = bv;
        }
#pragma unroll
        for (int mi = 0; mi < 2; ++mi)
#pragma unroll
            for (int ni = 0; ni < 4; ++ni)
                acc[mi][ni] = __builtin_amdgcn_mfma_f32_16x16x32_bf16(
                    af[mi], bfr[ni], acc[mi][ni], 0, 0, 0);
    }
    const int quad = lane >> 4, cl = lane & 15;
#pragma unroll
    for (int mi = 0; mi < 2; ++mi)
#pragma unroll
        for (int ni = 0; ni < 4; ++ni)
#pragma unroll
            for (int r = 0; r < 4; ++r)
                Ub[(size_t)(bm + mi * 16 + quad * 4 + r) * DH + w * 64 + ni * 16 + cl]
                    = f2bf(acc[mi][ni][r]);
}

// ---- fused: proj GEMM + U0 (blocks 0..NPROJ) | H scan (rest) — round-5 verbatim ----
__global__ __launch_bounds__(256) void scan_proj(const float* __restrict__ H,
                                                 const float* __restrict__ X,
                                                 const float* __restrict__ Wp,
                                                 const float* __restrict__ W0,
                                                 float* __restrict__ Xh,
                                                 unsigned short* __restrict__ Ub,
                                                 int* __restrict__ edge_cnt,
                                                 int* __restrict__ node_cnt,
                                                 int* __restrict__ edge_list,
                                                 int* __restrict__ node_list) {
    __shared__ short AsBs[1024 + 8192];
    const int tid = threadIdx.x;
    if (blockIdx.x >= NPROJ) {
        const int w = tid >> 6, lane = tid & 63;
        const int v    = (blockIdx.x - NPROJ) * 2 + (w >> 1);
        const int half = w & 1;
        const f32x4v* H4 = (const f32x4v*)(H + (size_t)v * NE) + half * 512;
        f32x4v h[8];
#pragma unroll
        for (int it = 0; it < 8; ++it)
            h[it] = __builtin_nontemporal_load(&H4[lane + 64 * it]);
        unsigned m = 0u;
#pragma unroll
        for (int it = 0; it < 8; ++it) {
#pragma unroll
            for (int c = 0; c < 4; ++c)
                m |= (h[it][c] != 0.0f ? 1u : 0u) << (it * 4 + c);
        }
        int n = __builtin_popcount(m);
        int pre = n;
#pragma unroll
        for (int o = 1; o < 64; o <<= 1) {
            int t = __shfl_up(pre, o, 64);
            if (lane >= o) pre += t;
        }
        int total = __shfl(pre, 63, 64);
        int local = pre - n;
        int base = 0;
        if (lane == 0 && total > 0) base = atomicAdd(&node_cnt[v], total);
        base = __shfl(base, 0, 64) + local;
        const int ebase = half * 2048 + 4 * lane;
        int e_arr[4] = {0, 0, 0, 0};
        {
            unsigned mm = m;
#pragma unroll
            for (int u = 0; u < 4; ++u) {
                if (mm) {
                    int j = __builtin_ctz(mm);
                    mm &= mm - 1;
                    e_arr[u] = ebase + 256 * (j >> 2) + (j & 3);
                }
            }
        }
        int s_arr[4];
#pragma unroll
        for (int u = 0; u < 4; ++u)
            s_arr[u] = (u < n) ? atomicAdd(&edge_cnt[e_arr[u] << 4], 1) : 0;
#pragma unroll
        for (int u = 0; u < 4; ++u) {
            if (u < n) {
                if (s_arr[u] < CAP_E) edge_list[e_arr[u] * CAP_E + s_arr[u]] = v;
                int idx = base + u;
                if (idx < CAP_V) node_list[v * CAP_V + idx] = e_arr[u];
            }
        }
        if (n > 4) {
            unsigned mm = m;
            mm &= mm - 1; mm &= mm - 1; mm &= mm - 1; mm &= mm - 1;
            int k = 4;
            while (mm) {
                int j = __builtin_ctz(mm); mm &= mm - 1;
                int ee = ebase + 256 * (j >> 2) + (j & 3);
                int gc = atomicAdd(&edge_cnt[ee << 4], 1);
                if (gc < CAP_E) edge_list[ee * CAP_E + gc] = v;
                int idx = base + k;
                if (idx < CAP_V) node_list[v * CAP_V + idx] = ee;
                ++k;
            }
        }
        return;
    }
    short* As = AsBs;
    short* Bs = AsBs + 1024;
    const int K = DIN;
    const int lane = tid & 63;
    const int w    = tid >> 6;
    const int bm   = blockIdx.x * 32;
    const int swz  = lane ^ ((lane >> 3) & 6);
    float4 ar, br[8];
    ar = *(const float4*)(X + (size_t)(bm + (tid >> 3)) * K + ((tid & 7) << 2));
#pragma unroll
    for (int it = 0; it < 8; ++it) {
        int i = tid + it * 256;
        br[it] = *(const float4*)(Wp + (size_t)(i >> 3) * K + ((i & 7) << 2));
    }
    f32x4 acc[2][4];
#pragma unroll
    for (int mi = 0; mi < 2; ++mi)
#pragma unroll
        for (int ni = 0; ni < 4; ++ni) acc[mi][ni] = (f32x4){0.f, 0.f, 0.f, 0.f};
    for (int k0 = 0; k0 < K; k0 += 32) {
        __syncthreads();
        {
            int row = tid >> 3, kk = (tid & 7) << 2;
            int quad = kk >> 3, j = kk & 7;
            int ln = (row & 15) + (quad << 4);
            int pp = ln ^ ((ln >> 3) & 6);
            ushort4 u = {f2bf(ar.x), f2bf(ar.y), f2bf(ar.z), f2bf(ar.w)};
            *(ushort4*)&As[(row >> 4) * 512 + pp * 8 + j] = u;
        }
#pragma unroll
        for (int it = 0; it < 8; ++it) {
            int i = tid + it * 256;
            int row = i >> 3, kk = (i & 7) << 2;
            int quad = kk >> 3, j = kk & 7;
            int ln = (row & 15) + (quad << 4);
            int pp = ln ^ ((ln >> 3) & 6);
            float4 v = br[it];
            ushort4 u = {f2bf(v.x), f2bf(v.y), f2bf(v.z), f2bf(v.w)};
            *(ushort4*)&Bs[(row >> 4) * 512 + pp * 8 + j] = u;
        }
        __syncthreads();
        if (k0 + 32 < K) {
            int kn = k0 + 32;
            ar = *(const float4*)(X + (size_t)(bm + (tid >> 3)) * K + kn + ((tid & 7) << 2));
#pragma unroll
            for (int it = 0; it < 8; ++it) {
                int i = tid + it * 256;
                br[it] = *(const float4*)(Wp + (size_t)(i >> 3) * K + kn + ((i & 7) << 2));
            }
        }
        bf16x8 af[2], bfr[4];
        af[0] = *(const bf16x8*)&As[0 * 512 + swz * 8];
        af[1] = *(const bf16x8*)&As[1 * 512 + swz * 8];
#pragma unroll
        for (int ni = 0; ni < 4; ++ni)
            bfr[ni] = *(const bf16x8*)&Bs[(w * 4 + ni) * 512 + swz * 8];
#pragma unroll
        for (int mi = 0; mi < 2; ++mi)
#pragma unroll
            for (int ni = 0; ni < 4; ++ni)
                acc[mi][ni] = __builtin_amdgcn_mfma_f32_16x16x32_bf16(
                    af[mi], bfr[ni], acc[mi][ni], 0, 0, 0);
    }
    const int quad = lane >> 4, cl = lane & 15;
    __syncthreads();
#pragma unroll
    for (int mi = 0; mi < 2; ++mi)
#pragma unroll
        for (int ni = 0; ni < 4; ++ni)
#pragma unroll
            for (int r = 0; r < 4; ++r) {
                float v = acc[mi][ni][r];
                int rl  = mi * 16 + quad * 4 + r;
                int col = w * 64 + ni * 16 + cl;
                Xh[(size_t)(bm + rl) * DH + col] = v;
                int kc = col >> 5, kk = col & 31;
                int q2 = kk >> 3, j = kk & 7;
                int ln = (rl & 15) + (q2 << 4);
                int pp = ln ^ ((ln >> 3) & 6);
                AsBs[(mi * 8 + kc) * 512 + pp * 8 + j] = (short)f2bf(v);
            }
    __syncthreads();
    u_gemm_from_lds(AsBs, W0, Ub, bm, tid);
}

// ------- gemm_u (round-0 verbatim) -------
__global__ __launch_bounds__(256) void gemm_u(const unsigned short* __restrict__ A,
                                              const float* __restrict__ W,
                                              unsigned short* __restrict__ U) {
    const int K = DH;
    __shared__ short As[2048];
    __shared__ short Bs[16384];
    const int tid  = threadIdx.x;
    const int lane = tid & 63;
    const int w    = tid >> 6;
    const int bm   = blockIdx.x * 32;
    const int swz  = lane ^ ((lane >> 3) & 6);

    uint4 ar; float4 br[16];
    ar = *(const uint4*)(A + (size_t)(bm + (tid >> 3)) * K + ((tid & 7) << 3));
#pragma unroll
    for (int it = 0; it < 16; ++it) {
        int i = tid + it * 256;
        br[it] = *(const float4*)(W + (size_t)(i >> 4) * K + ((i & 15) << 2));
    }
    f32x4 acc[2][4];
#pragma unroll
    for (int mi = 0; mi < 2; ++mi)
#pragma unroll
        for (int ni = 0; ni < 4; ++ni) acc[mi][ni] = (f32x4){0.f, 0.f, 0.f, 0.f};

    for (int k0 = 0; k0 < K; k0 += 64) {
        __syncthreads();
        {
            int row = tid >> 3, kq = tid & 7;
            int kc = kq >> 2, quad = kq & 3;
            int ln = (row & 15) + (quad << 4);
            int pp = ln ^ ((ln >> 3) & 6);
            *(uint4*)&As[((row >> 4) * 2 + kc) * 512 + pp * 8] = ar;
        }
#pragma unroll
        for (int it = 0; it < 16; ++it) {
            int i = tid + it * 256;
            int row = i >> 4, kk = (i & 15) << 2;
            int kc = kk >> 5, quad = (kk >> 3) & 3, j = kk & 7;
            int ln = (row & 15) + (quad << 4);
            int pp = ln ^ ((ln >> 3) & 6);
            float4 v = br[it];
            ushort4 u = {f2bf(v.x), f2bf(v.y), f2bf(v.z), f2bf(v.w)};
            *(ushort4*)&Bs[((row >> 4) * 2 + kc) * 512 + pp * 8 + j] = u;
        }
        __syncthreads();
        if (k0 + 64 < K) {
            int kn = k0 + 64;
            ar = *(const uint4*)(A + (size_t)(bm + (tid >> 3)) * K + kn + ((tid & 7) << 3));
#pragma unroll
            for (int it = 0; it < 16; ++it) {
                int i = tid + it * 256;
                br[it] = *(const float4*)(W + (size_t)(i >> 4) * K + kn + ((i & 15) << 2));
            }
        }
#pragma unroll
        for (int kc = 0; kc < 2; ++kc) {
            bf16x8 af[2], bfr[4];
            af[0] = *(const bf16x8*)&As[(0 * 2 + kc) * 512 + swz * 8];
            af[1] = *(const bf16x8*)&As[(1 * 2 + kc) * 512 + swz * 8];
#pragma unroll
            for (int ni = 0; ni < 4; ++ni)
                bfr[ni] = *(const bf16x8*)&Bs[((w * 4 + ni) * 2 + kc) * 512 + swz * 8];
#pragma unroll
            for (int mi = 0; mi < 2; ++mi)
#pragma unroll
                for (int ni = 0; ni < 4; ++ni)
                    acc[mi][ni] = __builtin_amdgcn_mfma_f32_16x16x32_bf16(
                        af[mi], bfr[ni], acc[mi][ni], 0, 0, 0);
        }
    }
    const int quad = lane >> 4, cl = lane & 15;
#pragma unroll
    for (int mi = 0; mi < 2; ++mi)
#pragma unroll
        for (int ni = 0; ni < 4; ++ni)
#pragma unroll
            for (int r = 0; r < 4; ++r)
                U[(size_t)(bm + mi * 16 + quad * 4 + r) * DH + w * 64 + ni * 16 + cl]
                    = f2bf(acc[mi][ni][r]);
}

// ---- Yb[e,:] = bf16( rsqrt(de) * sum_{v in e} rsqrt(dv) * Ub[v,:] ) (round-0 verbatim) ----
__global__ __launch_bounds__(64) void edge_gather(const unsigned short* __restrict__ Ub,
                                                  const int* __restrict__ edge_cnt,
                                                  const int* __restrict__ edge_list,
                                                  const int* __restrict__ node_cnt,
                                                  unsigned short* __restrict__ Yb) {
    int e = blockIdx.x;
    int tid = threadIdx.x;
    __shared__ int   lv[CAP_E];
    __shared__ float lc[CAP_E];
    int tc = edge_cnt[e << 4];
    int cnt = min(tc, CAP_E);
    for (int j = tid; j < cnt; j += 64) {
        int v = edge_list[e * CAP_E + j];
        lv[j] = v * (DH / 4);
        lc[j] = rsqrtf((float)node_cnt[v]);
    }
    __syncthreads();
    const ushort4* X4 = (const ushort4*)Ub;
    float4 a[8];
#pragma unroll
    for (int u = 0; u < 8; ++u) a[u] = (float4){0.f, 0.f, 0.f, 0.f};
    int i = 0;
    for (; i + 8 <= cnt; i += 8) {
#pragma unroll
        for (int u = 0; u < 8; ++u) {
            ushort4 h = X4[lv[i + u] + tid]; float c = lc[i + u];
            a[u].x = fmaf(c, b2f(h.x), a[u].x); a[u].y = fmaf(c, b2f(h.y), a[u].y);
            a[u].z = fmaf(c, b2f(h.z), a[u].z); a[u].w = fmaf(c, b2f(h.w), a[u].w);
        }
    }
    for (; i < cnt; ++i) {
        ushort4 h = X4[lv[i] + tid]; float c = lc[i];
        a[0].x = fmaf(c, b2f(h.x), a[0].x); a[0].y = fmaf(c, b2f(h.y), a[0].y);
        a[0].z = fmaf(c, b2f(h.z), a[0].z); a[0].w = fmaf(c, b2f(h.w), a[0].w);
    }
#pragma unroll
    for (int u = 4; u > 0; u >>= 1)
#pragma unroll
        for (int q = 0; q < u; ++q) {
            a[q].x += a[q + u].x; a[q].y += a[q + u].y;
            a[q].z += a[q + u].z; a[q].w += a[q + u].w;
        }
    float de = tc > 0 ? rsqrtf((float)tc) : 0.f;
    ushort4 o = {f2bf(de * a[0].x), f2bf(de * a[0].y),
                 f2bf(de * a[0].z), f2bf(de * a[0].w)};
    ((ushort4*)Yb)[e * (DH / 4) + tid] = o;
}

// ---- layer-0 node gather + relu + residual + LayerNorm (round-0 verbatim) ----
__global__ __launch_bounds__(64) void node_ln(const unsigned short* __restrict__ Yb,
                                              const int* __restrict__ node_cnt,
                                              const int* __restrict__ node_list,
                                              const int* __restrict__ edge_cnt,
                                              float* __restrict__ Xh,
                                              unsigned short* __restrict__ Xhb,
                                              const float* __restrict__ g,
                                              const float* __restrict__ b) {
    int v = blockIdx.x;
    int tid = threadIdx.x;
    __shared__ int   le[CAP_V];
    __shared__ float lc[CAP_V];
    int tc = node_cnt[v];
    int cnt = min(tc, CAP_V);
    if (tid < cnt) {
        int e = node_list[v * CAP_V + tid];
        le[tid] = e * (DH / 4);
        lc[tid] = rsqrtf((float)edge_cnt[e << 4]);
    }
    __syncthreads();
    const ushort4* Y4 = (const ushort4*)Yb;
    float4 a[8];
#pragma unroll
    for (int u = 0; u < 8; ++u) a[u] = (float4){0.f, 0.f, 0.f, 0.f};
    int i = 0;
    for (; i + 8 <= cnt; i += 8) {
#pragma unroll
        for (int u = 0; u < 8; ++u) {
            ushort4 h = Y4[le[i + u] + tid]; float c = lc[i + u];
            a[u].x = fmaf(c, b2f(h.x), a[u].x); a[u].y = fmaf(c, b2f(h.y), a[u].y);
            a[u].z = fmaf(c, b2f(h.z), a[u].z); a[u].w = fmaf(c, b2f(h.w), a[u].w);
        }
    }
    for (; i < cnt; ++i) {
        ushort4 h = Y4[le[i] + tid]; float c = lc[i];
        a[0].x = fmaf(c, b2f(h.x), a[0].x); a[0].y = fmaf(c, b2f(h.y), a[0].y);
        a[0].z = fmaf(c, b2f(h.z), a[0].z); a[0].w = fmaf(c, b2f(h.w), a[0].w);
    }
#pragma unroll
    for (int u = 4; u > 0; u >>= 1)
#pragma unroll
        for (int q = 0; q < u; ++q) {
            a[q].x += a[q + u].x; a[q].y += a[q + u].y;
            a[q].z += a[q + u].z; a[q].w += a[q + u].w;
        }
    float dv = tc > 0 ? rsqrtf((float)tc) : 0.f;
    float4 xr = ((const float4*)Xh)[v * (DH / 4) + tid];
    float x0 = xr.x + fmaxf(dv * a[0].x, 0.f);
    float x1 = xr.y + fmaxf(dv * a[0].y, 0.f);
    float x2 = xr.z + fmaxf(dv * a[0].z, 0.f);
    float x3 = xr.w + fmaxf(dv * a[0].w, 0.f);
    float s = (x0 + x1) + (x2 + x3);
    float q = fmaf(x0, x0, fmaf(x1, x1, fmaf(x2, x2, x3 * x3)));
#pragma unroll
    for (int o = 1; o < 64; o <<= 1) {
        s += __shfl_xor(s, o, 64);
        q += __shfl_xor(q, o, 64);
    }
    float m = s * (1.0f / DH);
    float var = q * (1.0f / DH) - m * m;
    float rstd = rsqrtf(var + 1e-5f);
    float4 g4 = ((const float4*)g)[tid];
    float4 b4 = ((const float4*)b)[tid];
    float4 o;
    o.x = (x0 - m) * rstd * g4.x + b4.x;
    o.y = (x1 - m) * rstd * g4.y + b4.y;
    o.z = (x2 - m) * rstd * g4.z + b4.z;
    o.w = (x3 - m) * rstd * g4.w + b4.w;
    ((float4*)Xh)[v * (DH / 4) + tid] = o;
    ushort4 ob = {f2bf(o.x), f2bf(o.y), f2bf(o.z), f2bf(o.w)};
    ((ushort4*)Xhb)[v * (DH / 4) + tid] = ob;
}

// ---- layer-1 node gather + LN + FUSED per-node classifier dot:
//      q[v] = (bf16(LN_out) . Wc0, bf16(LN_out) . Wc1). No Xh/Xhb writeback —
//      the final output flows only through q. Same per-row math as node_ln;
//      dot matches pool_classify's per-lane mult + shfl_down tree exactly. ----
__global__ __launch_bounds__(64) void node_ln_q(const unsigned short* __restrict__ Yb,
                                                const int* __restrict__ node_cnt,
                                                const int* __restrict__ node_list,
                                                const int* __restrict__ edge_cnt,
                                                const float* __restrict__ Xh,
                                                const float* __restrict__ g,
                                                const float* __restrict__ b,
                                                const float* __restrict__ Wc,
                                                float2* __restrict__ qout) {
    int v = blockIdx.x;
    int tid = threadIdx.x;
    __shared__ int   le[CAP_V];
    __shared__ float lc[CAP_V];
    int tc = node_cnt[v];
    int cnt = min(tc, CAP_V);
    if (tid < cnt) {
        int e = node_list[v * CAP_V + tid];
        le[tid] = e * (DH / 4);
        lc[tid] = rsqrtf((float)edge_cnt[e << 4]);
    }
    __syncthreads();
    const ushort4* Y4 = (const ushort4*)Yb;
    float4 a[8];
#pragma unroll
    for (int u = 0; u < 8; ++u) a[u] = (float4){0.f, 0.f, 0.f, 0.f};
    int i = 0;
    for (; i + 8 <= cnt; i += 8) {
#pragma unroll
        for (int u = 0; u < 8; ++u) {
            ushort4 h = Y4[le[i + u] + tid]; float c = lc[i + u];
            a[u].x = fmaf(c, b2f(h.x), a[u].x); a[u].y = fmaf(c, b2f(h.y), a[u].y);
            a[u].z = fmaf(c, b2f(h.z), a[u].z); a[u].w = fmaf(c, b2f(h.w), a[u].w);
        }
    }
    for (; i < cnt; ++i) {
        ushort4 h = Y4[le[i] + tid]; float c = lc[i];
        a[0].x = fmaf(c, b2f(h.x), a[0].x); a[0].y = fmaf(c, b2f(h.y), a[0].y);
        a[0].z = fmaf(c, b2f(h.z), a[0].z); a[0].w = fmaf(c, b2f(h.w), a[0].w);
    }
#pragma unroll
    for (int u = 4; u > 0; u >>= 1)
#pragma unroll
        for (int q = 0; q < u; ++q) {
            a[q].x += a[q + u].x; a[q].y += a[q + u].y;
            a[q].z += a[q + u].z; a[q].w += a[q + u].w;
        }
    float dv = tc > 0 ? rsqrtf((float)tc) : 0.f;
    float4 xr = ((const float4*)Xh)[v * (DH / 4) + tid];
    float x0 = xr.x + fmaxf(dv * a[0].x, 0.f);
    float x1 = xr.y + fmaxf(dv * a[0].y, 0.f);
    float x2 = xr.z + fmaxf(dv * a[0].z, 0.f);
    float x3 = xr.w + fmaxf(dv * a[0].w, 0.f);
    float s = (x0 + x1) + (x2 + x3);
    float q = fmaf(x0, x0, fmaf(x1, x1, fmaf(x2, x2, x3 * x3)));
#pragma unroll
    for (int o = 1; o < 64; o <<= 1) {
        s += __shfl_xor(s, o, 64);
        q += __shfl_xor(q, o, 64);
    }
    float m = s * (1.0f / DH);
    float var = q * (1.0f / DH) - m * m;
    float rstd = rsqrtf(var + 1e-5f);
    float4 g4 = ((const float4*)g)[tid];
    float4 b4 = ((const float4*)b)[tid];
    // LN output, then round-trip through bf16 exactly as the old Xhb path did
    float o0 = b2f(f2bf((x0 - m) * rstd * g4.x + b4.x));
    float o1 = b2f(f2bf((x1 - m) * rstd * g4.y + b4.y));
    float o2 = b2f(f2bf((x2 - m) * rstd * g4.z + b4.z));
    float o3 = b2f(f2bf((x3 - m) * rstd * g4.w + b4.w));
    const float4* W4 = (const float4*)Wc;
    float4 w0 = W4[tid], w1 = W4[64 + tid];
    float p0 = o0 * w0.x + o1 * w0.y + o2 * w0.z + o3 * w0.w;
    float p1 = o0 * w1.x + o1 * w1.y + o2 * w1.z + o3 * w1.w;
#pragma unroll
    for (int off = 32; off > 0; off >>= 1) {
        p0 += __shfl_down(p0, off, 64);
        p1 += __shfl_down(p1, off, 64);
    }
    if (tid == 0) qout[v] = make_float2(p0, p1);
}

// ------- pool on per-node scalars: out[e] = softmax(mean_{v in e} q[v] + bc).
//         8 B gathered per member instead of 512 B (69x traffic cut). -------
__global__ __launch_bounds__(256) void pool_q(const float2* __restrict__ q,
                                              const int* __restrict__ edge_cnt,
                                              const int* __restrict__ edge_list,
                                              const float* __restrict__ bc,
                                              float* __restrict__ out) {
    const int tid = threadIdx.x;
    const int w = tid >> 6, lane = tid & 63;
    const int e = blockIdx.x * 4 + w;
    int tc = edge_cnt[e << 4];
    int cnt = min(tc, CAP_E);
    float s0 = 0.f, s1 = 0.f;
    for (int j = lane; j < cnt; j += 64) {
        int v = edge_list[e * CAP_E + j];
        float2 qq = q[v];
        s0 += qq.x; s1 += qq.y;
    }
#pragma unroll
    for (int o = 32; o > 0; o >>= 1) {
        s0 += __shfl_down(s0, o, 64);
        s1 += __shfl_down(s1, o, 64);
    }
    if (lane == 0) {
        float inv = tc > 0 ? 1.0f / (float)tc : 1.0f;
        float l0 = s0 * inv + bc[0], l1 = s1 * inv + bc[1];
        float mx = fmaxf(l0, l1);
        float e0 = expf(l0 - mx), e1 = expf(l1 - mx);
        float sden = 1.0f / (e0 + e1);
        out[e * 2 + 0] = e0 * sden;
        out[e * 2 + 1] = e1 * sden;
    }
}

extern "C" void kernel_launch(void* const* d_in, const int* in_sizes, int n_in,
                              void* d_out, int out_size, void* d_ws, size_t ws_size,
                              hipStream_t stream) {
    const float* X  = (const float*)d_in[0];
    const float* H  = (const float*)d_in[1];
    const float* Wp = (const float*)d_in[2];
    const float* W0 = (const float*)d_in[3];
    const float* W1 = (const float*)d_in[4];
    const float* g0 = (const float*)d_in[5];
    const float* b0 = (const float*)d_in[6];
    const float* g1 = (const float*)d_in[7];
    const float* b1 = (const float*)d_in[8];
    const float* Wc = (const float*)d_in[9];
    const float* bc = (const float*)d_in[10];
    float* out = (float*)d_out;

    float* ws = (float*)d_ws;
    float* Xh  = ws + OFF_XH;
    unsigned short* Ub  = (unsigned short*)(ws + OFF_UB);
    unsigned short* Yb  = (unsigned short*)(ws + OFF_YB);
    int* node_cnt  = (int*)(ws + OFF_NCNT);
    int* edge_cnt  = (int*)(ws + OFF_ECNT);
    int* edge_list = (int*)(ws + OFF_EL);
    int* node_list = (int*)(ws + OFF_NL);
    unsigned short* Xhb = (unsigned short*)(ws + OFF_XHB);
    float2* qbuf = (float2*)(ws + OFF_Q);

    // node_cnt and edge_cnt are contiguous: one memset for both
    hipMemsetAsync(node_cnt, 0, (size_t)(NV + NE * 16) * sizeof(int), stream);

    // stage A: proj GEMM + fused U0 (blocks 0..255, hides under the 4096-block scan)
    scan_proj<<<NPROJ + NSCAN, 256, 0, stream>>>(H, X, Wp, W0, Xh, Ub,
                                                 edge_cnt, node_cnt, edge_list, node_list);

    // layer 0 (U0 already in Ub)
    edge_gather<<<NE, 64, 0, stream>>>(Ub, edge_cnt, edge_list, node_cnt, Yb);
    node_ln<<<NV, 64, 0, stream>>>(Yb, node_cnt, node_list, edge_cnt,
                                   Xh, Xhb, g0, b0);
    // layer 1 (U1 from standalone high-occupancy gemm_u)
    gemm_u<<<NV / 32, 256, 0, stream>>>(Xhb, W1, Ub);
    edge_gather<<<NE, 64, 0, stream>>>(Ub, edge_cnt, edge_list, node_cnt, Yb);
    node_ln_q<<<NV, 64, 0, stream>>>(Yb, node_cnt, node_list, edge_cnt,
                                     Xh, g1, b1, Wc, qbuf);

    // pool on 8-byte per-node scalars
    pool_q<<<NE / 4, 256, 0, stream>>>(qbuf, edge_cnt, edge_list, bc, out);
}

// Round 10
// 280.517 us; speedup vs baseline: 1.0559x; 1.0025x over previous
//
#include <hip/hip_runtime.h>
#include <math.h>

#define NV 8192
#define NE 4096
#define DIN 512
#define DH 256
#define CAP_E 96
#define CAP_V 64
#define NPROJ (NV / 32)      // 256 proj-GEMM blocks
#define NSCAN (NV / 4)       // 2048 scan blocks (4 waves/block, wave-per-FULL-row)

// ---------------- workspace layout (float offsets) ----------------
#define OFF_XH   0                       // V*DH fp32 (residual)
#define OFF_UB   (OFF_XH + NV*DH)        // V*DH bf16 (U = Xh@W^T)
#define OFF_YB   (OFF_UB + NV*DH/2)      // E*DH bf16
#define OFF_NCNT (OFF_YB + NE*DH/2)      // V ints
#define OFF_ECNT (OFF_NCNT + NV)         // E*16 ints (line-padded counters)
#define OFF_EL   (OFF_ECNT + NE*16)      // E*CAP_E ints
#define OFF_NL   (OFF_EL + NE*CAP_E)     // V*CAP_V ints
#define OFF_XHB  (OFF_NL + NV*CAP_V)     // V*DH bf16 (layer-0 LN out, feeds gemm_u)
#define OFF_Q    (OFF_XHB + NV*DH/2)     // V float2: per-node classifier dots

using bf16x8 = __attribute__((ext_vector_type(8))) short;
using f32x4  = __attribute__((ext_vector_type(4))) float;
using f32x4v = __attribute__((ext_vector_type(4))) float;

__device__ inline unsigned short f2bf(float f) {   // round-to-nearest-even
    union { float f; unsigned u; } v; v.f = f;
    unsigned r = v.u + 0x7FFF + ((v.u >> 16) & 1);
    return (unsigned short)(r >> 16);
}
__device__ inline float b2f(unsigned short s) {
    union { unsigned u; float f; } v; v.u = ((unsigned)s) << 16; return v.f;
}

// ---- U-GEMM from an LDS-stashed 32x256 bf16 A-tile (verified rounds 4-9) ----
__device__ inline void u_gemm_from_lds(const short* __restrict__ sm,
                                       const float* __restrict__ W,
                                       unsigned short* __restrict__ Ub,
                                       int bm, int tid) {
    const int w = tid >> 6, lane = tid & 63;
    const int r15 = lane & 15, k8 = (lane >> 4) << 3;
    const int swz = lane ^ ((lane >> 3) & 6);
    f32x4 acc[2][4];
#pragma unroll
    for (int mi = 0; mi < 2; ++mi)
#pragma unroll
        for (int ni = 0; ni < 4; ++ni) acc[mi][ni] = (f32x4){0.f, 0.f, 0.f, 0.f};
#pragma unroll
    for (int kc = 0; kc < 8; ++kc) {
        bf16x8 af[2], bfr[4];
        af[0] = *(const bf16x8*)&sm[(0 * 8 + kc) * 512 + swz * 8];
        af[1] = *(const bf16x8*)&sm[(1 * 8 + kc) * 512 + swz * 8];
#pragma unroll
        for (int ni = 0; ni < 4; ++ni) {
            const float* wr = W + (size_t)(w * 64 + ni * 16 + r15) * DH + kc * 32 + k8;
            float4 b0 = *(const float4*)wr;
            float4 b1 = *(const float4*)(wr + 4);
            bf16x8 bv;
            bv[0] = (short)f2bf(b0.x); bv[1] = (short)f2bf(b0.y);
            bv[2] = (short)f2bf(b0.z); bv[3] = (short)f2bf(b0.w);
            bv[4] = (short)f2bf(b1.x); bv[5] = (short)f2bf(b1.y);
            bv[6] = (short)f2bf(b1.z); bv[7] = (short)f2bf(b1.w);
            bfr[ni] = bv;
        }
#pragma unroll
        for (int mi = 0; mi < 2; ++mi)
#pragma unroll
            for (int ni = 0; ni < 4; ++ni)
                acc[mi][ni] = __builtin_amdgcn_mfma_f32_16x16x32_bf16(
                    af[mi], bfr[ni], acc[mi][ni], 0, 0, 0);
    }
    const int quad = lane >> 4, cl = lane & 15;
#pragma unroll
    for (int mi = 0; mi < 2; ++mi)
#pragma unroll
        for (int ni = 0; ni < 4; ++ni)
#pragma unroll
            for (int r = 0; r < 4; ++r)
                Ub[(size_t)(bm + mi * 16 + quad * 4 + r) * DH + w * 64 + ni * 16 + cl]
                    = f2bf(acc[mi][ni][r]);
}

// ---- fused: blocks [0,NPROJ) proj GEMM + U0 (verbatim);
//      blocks [NPROJ, NPROJ+NSCAN): PIPELINED scan — wave per FULL row,
//      both 8KB load batches in flight before processing; node_cnt is a
//      plain store (single writer per row, no atomic round-trip). ----
__global__ __launch_bounds__(256) void scan_proj(const float* __restrict__ H,
                                                 const float* __restrict__ X,
                                                 const float* __restrict__ Wp,
                                                 const float* __restrict__ W0,
                                                 float* __restrict__ Xh,
                                                 unsigned short* __restrict__ Ub,
                                                 int* __restrict__ edge_cnt,
                                                 int* __restrict__ node_cnt,
                                                 int* __restrict__ edge_list,
                                                 int* __restrict__ node_list) {
    __shared__ short AsBs[1024 + 8192];
    const int tid = threadIdx.x;
    if (blockIdx.x >= NPROJ) {
        const int w = tid >> 6, lane = tid & 63;
        const int v = (blockIdx.x - NPROJ) * 4 + w;     // wave-per-full-row
        const f32x4v* H4 = (const f32x4v*)(H + (size_t)v * NE);
        f32x4v ha[8], hb[8];
#pragma unroll
        for (int it = 0; it < 8; ++it)
            ha[it] = __builtin_nontemporal_load(&H4[lane + 64 * it]);        // cols [0,2048)
#pragma unroll
        for (int it = 0; it < 8; ++it)
            hb[it] = __builtin_nontemporal_load(&H4[512 + lane + 64 * it]);  // cols [2048,4096)
        unsigned mA = 0u, mB = 0u;
#pragma unroll
        for (int it = 0; it < 8; ++it) {
#pragma unroll
            for (int c = 0; c < 4; ++c) {
                mA |= (ha[it][c] != 0.0f ? 1u : 0u) << (it * 4 + c);
                mB |= (hb[it][c] != 0.0f ? 1u : 0u) << (it * 4 + c);
            }
        }
        const int nA = __builtin_popcount(mA);
        const int nB = __builtin_popcount(mB);
        const int n = nA + nB;
        int pre = n;
#pragma unroll
        for (int o = 1; o < 64; o <<= 1) {
            int t = __shfl_up(pre, o, 64);
            if (lane >= o) pre += t;
        }
        int total = __shfl(pre, 63, 64);
        int local = pre - n;                 // exclusive scan base within the row
        if (lane == 0) node_cnt[v] = total;  // plain store: one wave owns the row
        const int ebA = 4 * lane, ebB = 2048 + 4 * lane;
        // ---- mask A (cols 0..2047) ----
        {
            int e_arr[4] = {0, 0, 0, 0};
            unsigned mm = mA;
#pragma unroll
            for (int u = 0; u < 4; ++u) {
                if (mm) {
                    int j = __builtin_ctz(mm); mm &= mm - 1;
                    e_arr[u] = ebA + 256 * (j >> 2) + (j & 3);
                }
            }
            int s_arr[4];
#pragma unroll
            for (int u = 0; u < 4; ++u)
                s_arr[u] = (u < nA) ? atomicAdd(&edge_cnt[e_arr[u] << 4], 1) : 0;
#pragma unroll
            for (int u = 0; u < 4; ++u) {
                if (u < nA) {
                    if (s_arr[u] < CAP_E) edge_list[e_arr[u] * CAP_E + s_arr[u]] = v;
                    int idx = local + u;
                    if (idx < CAP_V) node_list[v * CAP_V + idx] = e_arr[u];
                }
            }
            if (nA > 4) {
                unsigned m2 = mA;
                m2 &= m2 - 1; m2 &= m2 - 1; m2 &= m2 - 1; m2 &= m2 - 1;
                int k = local + 4;
                while (m2) {
                    int j = __builtin_ctz(m2); m2 &= m2 - 1;
                    int ee = ebA + 256 * (j >> 2) + (j & 3);
                    int gc = atomicAdd(&edge_cnt[ee << 4], 1);
                    if (gc < CAP_E) edge_list[ee * CAP_E + gc] = v;
                    if (k < CAP_V) node_list[v * CAP_V + k] = ee;
                    ++k;
                }
            }
        }
        // ---- mask B (cols 2048..4095); node indices continue at local+nA ----
        {
            int e_arr[4] = {0, 0, 0, 0};
            unsigned mm = mB;
#pragma unroll
            for (int u = 0; u < 4; ++u) {
                if (mm) {
                    int j = __builtin_ctz(mm); mm &= mm - 1;
                    e_arr[u] = ebB + 256 * (j >> 2) + (j & 3);
                }
            }
            int s_arr[4];
#pragma unroll
            for (int u = 0; u < 4; ++u)
                s_arr[u] = (u < nB) ? atomicAdd(&edge_cnt[e_arr[u] << 4], 1) : 0;
#pragma unroll
            for (int u = 0; u < 4; ++u) {
                if (u < nB) {
                    if (s_arr[u] < CAP_E) edge_list[e_arr[u] * CAP_E + s_arr[u]] = v;
                    int idx = local + nA + u;
                    if (idx < CAP_V) node_list[v * CAP_V + idx] = e_arr[u];
                }
            }
            if (nB > 4) {
                unsigned m2 = mB;
                m2 &= m2 - 1; m2 &= m2 - 1; m2 &= m2 - 1; m2 &= m2 - 1;
                int k = local + nA + 4;
                while (m2) {
                    int j = __builtin_ctz(m2); m2 &= m2 - 1;
                    int ee = ebB + 256 * (j >> 2) + (j & 3);
                    int gc = atomicAdd(&edge_cnt[ee << 4], 1);
                    if (gc < CAP_E) edge_list[ee * CAP_E + gc] = v;
                    if (k < CAP_V) node_list[v * CAP_V + k] = ee;
                    ++k;
                }
            }
        }
        return;
    }
    // ---------------- proj GEMM path (round-9 verbatim) ----------------
    short* As = AsBs;
    short* Bs = AsBs + 1024;
    const int K = DIN;
    const int lane = tid & 63;
    const int w    = tid >> 6;
    const int bm   = blockIdx.x * 32;
    const int swz  = lane ^ ((lane >> 3) & 6);
    float4 ar, br[8];
    ar = *(const float4*)(X + (size_t)(bm + (tid >> 3)) * K + ((tid & 7) << 2));
#pragma unroll
    for (int it = 0; it < 8; ++it) {
        int i = tid + it * 256;
        br[it] = *(const float4*)(Wp + (size_t)(i >> 3) * K + ((i & 7) << 2));
    }
    f32x4 acc[2][4];
#pragma unroll
    for (int mi = 0; mi < 2; ++mi)
#pragma unroll
        for (int ni = 0; ni < 4; ++ni) acc[mi][ni] = (f32x4){0.f, 0.f, 0.f, 0.f};
    for (int k0 = 0; k0 < K; k0 += 32) {
        __syncthreads();
        {
            int row = tid >> 3, kk = (tid & 7) << 2;
            int quad = kk >> 3, j = kk & 7;
            int ln = (row & 15) + (quad << 4);
            int pp = ln ^ ((ln >> 3) & 6);
            ushort4 u = {f2bf(ar.x), f2bf(ar.y), f2bf(ar.z), f2bf(ar.w)};
            *(ushort4*)&As[(row >> 4) * 512 + pp * 8 + j] = u;
        }
#pragma unroll
        for (int it = 0; it < 8; ++it) {
            int i = tid + it * 256;
            int row = i >> 3, kk = (i & 7) << 2;
            int quad = kk >> 3, j = kk & 7;
            int ln = (row & 15) + (quad << 4);
            int pp = ln ^ ((ln >> 3) & 6);
            float4 v = br[it];
            ushort4 u = {f2bf(v.x), f2bf(v.y), f2bf(v.z), f2bf(v.w)};
            *(ushort4*)&Bs[(row >> 4) * 512 + pp * 8 + j] = u;
        }
        __syncthreads();
        if (k0 + 32 < K) {
            int kn = k0 + 32;
            ar = *(const float4*)(X + (size_t)(bm + (tid >> 3)) * K + kn + ((tid & 7) << 2));
#pragma unroll
            for (int it = 0; it < 8; ++it) {
                int i = tid + it * 256;
                br[it] = *(const float4*)(Wp + (size_t)(i >> 3) * K + kn + ((i & 7) << 2));
            }
        }
        bf16x8 af[2], bfr[4];
        af[0] = *(const bf16x8*)&As[0 * 512 + swz * 8];
        af[1] = *(const bf16x8*)&As[1 * 512 + swz * 8];
#pragma unroll
        for (int ni = 0; ni < 4; ++ni)
            bfr[ni] = *(const bf16x8*)&Bs[(w * 4 + ni) * 512 + swz * 8];
#pragma unroll
        for (int mi = 0; mi < 2; ++mi)
#pragma unroll
            for (int ni = 0; ni < 4; ++ni)
                acc[mi][ni] = __builtin_amdgcn_mfma_f32_16x16x32_bf16(
                    af[mi], bfr[ni], acc[mi][ni], 0, 0, 0);
    }
    const int quad = lane >> 4, cl = lane & 15;
    __syncthreads();
#pragma unroll
    for (int mi = 0; mi < 2; ++mi)
#pragma unroll
        for (int ni = 0; ni < 4; ++ni)
#pragma unroll
            for (int r = 0; r < 4; ++r) {
                float v = acc[mi][ni][r];
                int rl  = mi * 16 + quad * 4 + r;
                int col = w * 64 + ni * 16 + cl;
                Xh[(size_t)(bm + rl) * DH + col] = v;
                int kc = col >> 5, kk = col & 31;
                int q2 = kk >> 3, j = kk & 7;
                int ln = (rl & 15) + (q2 << 4);
                int pp = ln ^ ((ln >> 3) & 6);
                AsBs[(mi * 8 + kc) * 512 + pp * 8 + j] = (short)f2bf(v);
            }
    __syncthreads();
    u_gemm_from_lds(AsBs, W0, Ub, bm, tid);
}

// ------- gemm_u (round-0 verbatim) -------
__global__ __launch_bounds__(256) void gemm_u(const unsigned short* __restrict__ A,
                                              const float* __restrict__ W,
                                              unsigned short* __restrict__ U) {
    const int K = DH;
    __shared__ short As[2048];
    __shared__ short Bs[16384];
    const int tid  = threadIdx.x;
    const int lane = tid & 63;
    const int w    = tid >> 6;
    const int bm   = blockIdx.x * 32;
    const int swz  = lane ^ ((lane >> 3) & 6);

    uint4 ar; float4 br[16];
    ar = *(const uint4*)(A + (size_t)(bm + (tid >> 3)) * K + ((tid & 7) << 3));
#pragma unroll
    for (int it = 0; it < 16; ++it) {
        int i = tid + it * 256;
        br[it] = *(const float4*)(W + (size_t)(i >> 4) * K + ((i & 15) << 2));
    }
    f32x4 acc[2][4];
#pragma unroll
    for (int mi = 0; mi < 2; ++mi)
#pragma unroll
        for (int ni = 0; ni < 4; ++ni) acc[mi][ni] = (f32x4){0.f, 0.f, 0.f, 0.f};

    for (int k0 = 0; k0 < K; k0 += 64) {
        __syncthreads();
        {
            int row = tid >> 3, kq = tid & 7;
            int kc = kq >> 2, quad = kq & 3;
            int ln = (row & 15) + (quad << 4);
            int pp = ln ^ ((ln >> 3) & 6);
            *(uint4*)&As[((row >> 4) * 2 + kc) * 512 + pp * 8] = ar;
        }
#pragma unroll
        for (int it = 0; it < 16; ++it) {
            int i = tid + it * 256;
            int row = i >> 4, kk = (i & 15) << 2;
            int kc = kk >> 5, quad = (kk >> 3) & 3, j = kk & 7;
            int ln = (row & 15) + (quad << 4);
            int pp = ln ^ ((ln >> 3) & 6);
            float4 v = br[it];
            ushort4 u = {f2bf(v.x), f2bf(v.y), f2bf(v.z), f2bf(v.w)};
            *(ushort4*)&Bs[((row >> 4) * 2 + kc) * 512 + pp * 8 + j] = u;
        }
        __syncthreads();
        if (k0 + 64 < K) {
            int kn = k0 + 64;
            ar = *(const uint4*)(A + (size_t)(bm + (tid >> 3)) * K + kn + ((tid & 7) << 3));
#pragma unroll
            for (int it = 0; it < 16; ++it) {
                int i = tid + it * 256;
                br[it] = *(const float4*)(W + (size_t)(i >> 4) * K + kn + ((i & 15) << 2));
            }
        }
#pragma unroll
        for (int kc = 0; kc < 2; ++kc) {
            bf16x8 af[2], bfr[4];
            af[0] = *(const bf16x8*)&As[(0 * 2 + kc) * 512 + swz * 8];
            af[1] = *(const bf16x8*)&As[(1 * 2 + kc) * 512 + swz * 8];
#pragma unroll
            for (int ni = 0; ni < 4; ++ni)
                bfr[ni] = *(const bf16x8*)&Bs[((w * 4 + ni) * 2 + kc) * 512 + swz * 8];
#pragma unroll
            for (int mi = 0; mi < 2; ++mi)
#pragma unroll
                for (int ni = 0; ni < 4; ++ni)
                    acc[mi][ni] = __builtin_amdgcn_mfma_f32_16x16x32_bf16(
                        af[mi], bfr[ni], acc[mi][ni], 0, 0, 0);
        }
    }
    const int quad = lane >> 4, cl = lane & 15;
#pragma unroll
    for (int mi = 0; mi < 2; ++mi)
#pragma unroll
        for (int ni = 0; ni < 4; ++ni)
#pragma unroll
            for (int r = 0; r < 4; ++r)
                U[(size_t)(bm + mi * 16 + quad * 4 + r) * DH + w * 64 + ni * 16 + cl]
                    = f2bf(acc[mi][ni][r]);
}

// ---- Yb[e,:] = bf16( rsqrt(de) * sum_{v in e} rsqrt(dv) * Ub[v,:] ) (round-0 verbatim) ----
__global__ __launch_bounds__(64) void edge_gather(const unsigned short* __restrict__ Ub,
                                                  const int* __restrict__ edge_cnt,
                                                  const int* __restrict__ edge_list,
                                                  const int* __restrict__ node_cnt,
                                                  unsigned short* __restrict__ Yb) {
    int e = blockIdx.x;
    int tid = threadIdx.x;
    __shared__ int   lv[CAP_E];
    __shared__ float lc[CAP_E];
    int tc = edge_cnt[e << 4];
    int cnt = min(tc, CAP_E);
    for (int j = tid; j < cnt; j += 64) {
        int v = edge_list[e * CAP_E + j];
        lv[j] = v * (DH / 4);
        lc[j] = rsqrtf((float)node_cnt[v]);
    }
    __syncthreads();
    const ushort4* X4 = (const ushort4*)Ub;
    float4 a[8];
#pragma unroll
    for (int u = 0; u < 8; ++u) a[u] = (float4){0.f, 0.f, 0.f, 0.f};
    int i = 0;
    for (; i + 8 <= cnt; i += 8) {
#pragma unroll
        for (int u = 0; u < 8; ++u) {
            ushort4 h = X4[lv[i + u] + tid]; float c = lc[i + u];
            a[u].x = fmaf(c, b2f(h.x), a[u].x); a[u].y = fmaf(c, b2f(h.y), a[u].y);
            a[u].z = fmaf(c, b2f(h.z), a[u].z); a[u].w = fmaf(c, b2f(h.w), a[u].w);
        }
    }
    for (; i < cnt; ++i) {
        ushort4 h = X4[lv[i] + tid]; float c = lc[i];
        a[0].x = fmaf(c, b2f(h.x), a[0].x); a[0].y = fmaf(c, b2f(h.y), a[0].y);
        a[0].z = fmaf(c, b2f(h.z), a[0].z); a[0].w = fmaf(c, b2f(h.w), a[0].w);
    }
#pragma unroll
    for (int u = 4; u > 0; u >>= 1)
#pragma unroll
        for (int q = 0; q < u; ++q) {
            a[q].x += a[q + u].x; a[q].y += a[q + u].y;
            a[q].z += a[q + u].z; a[q].w += a[q + u].w;
        }
    float de = tc > 0 ? rsqrtf((float)tc) : 0.f;
    ushort4 o = {f2bf(de * a[0].x), f2bf(de * a[0].y),
                 f2bf(de * a[0].z), f2bf(de * a[0].w)};
    ((ushort4*)Yb)[e * (DH / 4) + tid] = o;
}

// ---- layer-0 node gather + relu + residual + LayerNorm (round-0 verbatim) ----
__global__ __launch_bounds__(64) void node_ln(const unsigned short* __restrict__ Yb,
                                              const int* __restrict__ node_cnt,
                                              const int* __restrict__ node_list,
                                              const int* __restrict__ edge_cnt,
                                              float* __restrict__ Xh,
                                              unsigned short* __restrict__ Xhb,
                                              const float* __restrict__ g,
                                              const float* __restrict__ b) {
    int v = blockIdx.x;
    int tid = threadIdx.x;
    __shared__ int   le[CAP_V];
    __shared__ float lc[CAP_V];
    int tc = node_cnt[v];
    int cnt = min(tc, CAP_V);
    if (tid < cnt) {
        int e = node_list[v * CAP_V + tid];
        le[tid] = e * (DH / 4);
        lc[tid] = rsqrtf((float)edge_cnt[e << 4]);
    }
    __syncthreads();
    const ushort4* Y4 = (const ushort4*)Yb;
    float4 a[8];
#pragma unroll
    for (int u = 0; u < 8; ++u) a[u] = (float4){0.f, 0.f, 0.f, 0.f};
    int i = 0;
    for (; i + 8 <= cnt; i += 8) {
#pragma unroll
        for (int u = 0; u < 8; ++u) {
            ushort4 h = Y4[le[i + u] + tid]; float c = lc[i + u];
            a[u].x = fmaf(c, b2f(h.x), a[u].x); a[u].y = fmaf(c, b2f(h.y), a[u].y);
            a[u].z = fmaf(c, b2f(h.z), a[u].z); a[u].w = fmaf(c, b2f(h.w), a[u].w);
        }
    }
    for (; i < cnt; ++i) {
        ushort4 h = Y4[le[i] + tid]; float c = lc[i];
        a[0].x = fmaf(c, b2f(h.x), a[0].x); a[0].y = fmaf(c, b2f(h.y), a[0].y);
        a[0].z = fmaf(c, b2f(h.z), a[0].z); a[0].w = fmaf(c, b2f(h.w), a[0].w);
    }
#pragma unroll
    for (int u = 4; u > 0; u >>= 1)
#pragma unroll
        for (int q = 0; q < u; ++q) {
            a[q].x += a[q + u].x; a[q].y += a[q + u].y;
            a[q].z += a[q + u].z; a[q].w += a[q + u].w;
        }
    float dv = tc > 0 ? rsqrtf((float)tc) : 0.f;
    float4 xr = ((const float4*)Xh)[v * (DH / 4) + tid];
    float x0 = xr.x + fmaxf(dv * a[0].x, 0.f);
    float x1 = xr.y + fmaxf(dv * a[0].y, 0.f);
    float x2 = xr.z + fmaxf(dv * a[0].z, 0.f);
    float x3 = xr.w + fmaxf(dv * a[0].w, 0.f);
    float s = (x0 + x1) + (x2 + x3);
    float q = fmaf(x0, x0, fmaf(x1, x1, fmaf(x2, x2, x3 * x3)));
#pragma unroll
    for (int o = 1; o < 64; o <<= 1) {
        s += __shfl_xor(s, o, 64);
        q += __shfl_xor(q, o, 64);
    }
    float m = s * (1.0f / DH);
    float var = q * (1.0f / DH) - m * m;
    float rstd = rsqrtf(var + 1e-5f);
    float4 g4 = ((const float4*)g)[tid];
    float4 b4 = ((const float4*)b)[tid];
    float4 o;
    o.x = (x0 - m) * rstd * g4.x + b4.x;
    o.y = (x1 - m) * rstd * g4.y + b4.y;
    o.z = (x2 - m) * rstd * g4.z + b4.z;
    o.w = (x3 - m) * rstd * g4.w + b4.w;
    ((float4*)Xh)[v * (DH / 4) + tid] = o;
    ushort4 ob = {f2bf(o.x), f2bf(o.y), f2bf(o.z), f2bf(o.w)};
    ((ushort4*)Xhb)[v * (DH / 4) + tid] = ob;
}

// ---- layer-1 node gather + LN + fused per-node classifier dot (round-9 verbatim) ----
__global__ __launch_bounds__(64) void node_ln_q(const unsigned short* __restrict__ Yb,
                                                const int* __restrict__ node_cnt,
                                                const int* __restrict__ node_list,
                                                const int* __restrict__ edge_cnt,
                                                const float* __restrict__ Xh,
                                                const float* __restrict__ g,
                                                const float* __restrict__ b,
                                                const float* __restrict__ Wc,
                                                float2* __restrict__ qout) {
    int v = blockIdx.x;
    int tid = threadIdx.x;
    __shared__ int   le[CAP_V];
    __shared__ float lc[CAP_V];
    int tc = node_cnt[v];
    int cnt = min(tc, CAP_V);
    if (tid < cnt) {
        int e = node_list[v * CAP_V + tid];
        le[tid] = e * (DH / 4);
        lc[tid] = rsqrtf((float)edge_cnt[e << 4]);
    }
    __syncthreads();
    const ushort4* Y4 = (const ushort4*)Yb;
    float4 a[8];
#pragma unroll
    for (int u = 0; u < 8; ++u) a[u] = (float4){0.f, 0.f, 0.f, 0.f};
    int i = 0;
    for (; i + 8 <= cnt; i += 8) {
#pragma unroll
        for (int u = 0; u < 8; ++u) {
            ushort4 h = Y4[le[i + u] + tid]; float c = lc[i + u];
            a[u].x = fmaf(c, b2f(h.x), a[u].x); a[u].y = fmaf(c, b2f(h.y), a[u].y);
            a[u].z = fmaf(c, b2f(h.z), a[u].z); a[u].w = fmaf(c, b2f(h.w), a[u].w);
        }
    }
    for (; i < cnt; ++i) {
        ushort4 h = Y4[le[i] + tid]; float c = lc[i];
        a[0].x = fmaf(c, b2f(h.x), a[0].x); a[0].y = fmaf(c, b2f(h.y), a[0].y);
        a[0].z = fmaf(c, b2f(h.z), a[0].z); a[0].w = fmaf(c, b2f(h.w), a[0].w);
    }
#pragma unroll
    for (int u = 4; u > 0; u >>= 1)
#pragma unroll
        for (int q = 0; q < u; ++q) {
            a[q].x += a[q + u].x; a[q].y += a[q + u].y;
            a[q].z += a[q + u].z; a[q].w += a[q + u].w;
        }
    float dv = tc > 0 ? rsqrtf((float)tc) : 0.f;
    float4 xr = ((const float4*)Xh)[v * (DH / 4) + tid];
    float x0 = xr.x + fmaxf(dv * a[0].x, 0.f);
    float x1 = xr.y + fmaxf(dv * a[0].y, 0.f);
    float x2 = xr.z + fmaxf(dv * a[0].z, 0.f);
    float x3 = xr.w + fmaxf(dv * a[0].w, 0.f);
    float s = (x0 + x1) + (x2 + x3);
    float q = fmaf(x0, x0, fmaf(x1, x1, fmaf(x2, x2, x3 * x3)));
#pragma unroll
    for (int o = 1; o < 64; o <<= 1) {
        s += __shfl_xor(s, o, 64);
        q += __shfl_xor(q, o, 64);
    }
    float m = s * (1.0f / DH);
    float var = q * (1.0f / DH) - m * m;
    float rstd = rsqrtf(var + 1e-5f);
    float4 g4 = ((const float4*)g)[tid];
    float4 b4 = ((const float4*)b)[tid];
    float o0 = b2f(f2bf((x0 - m) * rstd * g4.x + b4.x));
    float o1 = b2f(f2bf((x1 - m) * rstd * g4.y + b4.y));
    float o2 = b2f(f2bf((x2 - m) * rstd * g4.z + b4.z));
    float o3 = b2f(f2bf((x3 - m) * rstd * g4.w + b4.w));
    const float4* W4 = (const float4*)Wc;
    float4 w0 = W4[tid], w1 = W4[64 + tid];
    float p0 = o0 * w0.x + o1 * w0.y + o2 * w0.z + o3 * w0.w;
    float p1 = o0 * w1.x + o1 * w1.y + o2 * w1.z + o3 * w1.w;
#pragma unroll
    for (int off = 32; off > 0; off >>= 1) {
        p0 += __shfl_down(p0, off, 64);
        p1 += __shfl_down(p1, off, 64);
    }
    if (tid == 0) qout[v] = make_float2(p0, p1);
}

// ------- pool on per-node scalars (round-9 verbatim) -------
__global__ __launch_bounds__(256) void pool_q(const float2* __restrict__ q,
                                              const int* __restrict__ edge_cnt,
                                              const int* __restrict__ edge_list,
                                              const float* __restrict__ bc,
                                              float* __restrict__ out) {
    const int tid = threadIdx.x;
    const int w = tid >> 6, lane = tid & 63;
    const int e = blockIdx.x * 4 + w;
    int tc = edge_cnt[e << 4];
    int cnt = min(tc, CAP_E);
    float s0 = 0.f, s1 = 0.f;
    for (int j = lane; j < cnt; j += 64) {
        int v = edge_list[e * CAP_E + j];
        float2 qq = q[v];
        s0 += qq.x; s1 += qq.y;
    }
#pragma unroll
    for (int o = 32; o > 0; o >>= 1) {
        s0 += __shfl_down(s0, o, 64);
        s1 += __shfl_down(s1, o, 64);
    }
    if (lane == 0) {
        float inv = tc > 0 ? 1.0f / (float)tc : 1.0f;
        float l0 = s0 * inv + bc[0], l1 = s1 * inv + bc[1];
        float mx = fmaxf(l0, l1);
        float e0 = expf(l0 - mx), e1 = expf(l1 - mx);
        float sden = 1.0f / (e0 + e1);
        out[e * 2 + 0] = e0 * sden;
        out[e * 2 + 1] = e1 * sden;
    }
}

extern "C" void kernel_launch(void* const* d_in, const int* in_sizes, int n_in,
                              void* d_out, int out_size, void* d_ws, size_t ws_size,
                              hipStream_t stream) {
    const float* X  = (const float*)d_in[0];
    const float* H  = (const float*)d_in[1];
    const float* Wp = (const float*)d_in[2];
    const float* W0 = (const float*)d_in[3];
    const float* W1 = (const float*)d_in[4];
    const float* g0 = (const float*)d_in[5];
    const float* b0 = (const float*)d_in[6];
    const float* g1 = (const float*)d_in[7];
    const float* b1 = (const float*)d_in[8];
    const float* Wc = (const float*)d_in[9];
    const float* bc = (const float*)d_in[10];
    float* out = (float*)d_out;

    float* ws = (float*)d_ws;
    float* Xh  = ws + OFF_XH;
    unsigned short* Ub  = (unsigned short*)(ws + OFF_UB);
    unsigned short* Yb  = (unsigned short*)(ws + OFF_YB);
    int* node_cnt  = (int*)(ws + OFF_NCNT);
    int* edge_cnt  = (int*)(ws + OFF_ECNT);
    int* edge_list = (int*)(ws + OFF_EL);
    int* node_list = (int*)(ws + OFF_NL);
    unsigned short* Xhb = (unsigned short*)(ws + OFF_XHB);
    float2* qbuf = (float2*)(ws + OFF_Q);

    // node_cnt and edge_cnt are contiguous: one memset for both
    hipMemsetAsync(node_cnt, 0, (size_t)(NV + NE * 16) * sizeof(int), stream);

    // stage A: proj GEMM + fused U0 | pipelined full-row scan
    scan_proj<<<NPROJ + NSCAN, 256, 0, stream>>>(H, X, Wp, W0, Xh, Ub,
                                                 edge_cnt, node_cnt, edge_list, node_list);

    // layer 0 (U0 already in Ub)
    edge_gather<<<NE, 64, 0, stream>>>(Ub, edge_cnt, edge_list, node_cnt, Yb);
    node_ln<<<NV, 64, 0, stream>>>(Yb, node_cnt, node_list, edge_cnt,
                                   Xh, Xhb, g0, b0);
    // layer 1 (U1 from standalone high-occupancy gemm_u)
    gemm_u<<<NV / 32, 256, 0, stream>>>(Xhb, W1, Ub);
    edge_gather<<<NE, 64, 0, stream>>>(Ub, edge_cnt, edge_list, node_cnt, Yb);
    node_ln_q<<<NV, 64, 0, stream>>>(Yb, node_cnt, node_list, edge_cnt,
                                     Xh, g1, b1, Wc, qbuf);

    // pool on 8-byte per-node scalars
    pool_q<<<NE / 4, 256, 0, stream>>>(qbuf, edge_cnt, edge_list, bc, out);
}